// Round 9
// baseline (101.917 us; speedup 1.0000x reference)
//
#include <hip/hip_runtime.h>
#include <hip/hip_bf16.h>
#include <math.h>

typedef __attribute__((ext_vector_type(4)))  short short4v;
typedef __attribute__((ext_vector_type(8)))  short short8;
typedef __attribute__((ext_vector_type(16))) float f32x16;

#define B_   2
#define N_   768
#define CN_  384
#define H_   12
#define INF_ 100000.0f
#define EPS_ 1e-7f

// ---------------- workspace layout (f32-slot offsets) ----------------
// PROJ f32 [1536][1152]  at 0        (dead after pack2; tail reused)
//   Og  bf16 [1536][192] at 589824
//   OPg bf16 [1536][288] at 737280
// Qf  bf16 [24][768][32] at 1769472
// Kf  bf16 [24][768][32] at 2064384
// Vt  bf16 [24][64][768] at 2359296  (rows 40..63 never written; garbage is
//     confined to discarded acc1 regs 4..15 -- merge stores r<20 only)
// SB  bf16 [1536][384]   at 2949120  (s in bf16)
// WB  bf16 [1152][384]   at 3244032  (w_q|w_kv|w_qp|w_kvp rows, bf16)
// WOB bf16 [384][576]    at 3465216  (w_out bf16)
// MB  bf16 [2][24][24][64][16] at 3575808
#define OFF_PROJ 0
#define OFF_O    589824
#define OFF_OP   737280
#define OFF_QF   1769472
#define OFF_KF   2064384
#define OFF_VT   2359296
#define OFF_SB   2949120
#define OFF_WB   3244032
#define OFF_WOB  3465216
#define OFF_MB   3575808

__device__ inline float b2f(unsigned short u) {
    union { unsigned int i; float f; } x; x.i = ((unsigned int)u) << 16; return x.f;
}
__device__ inline unsigned short f2b(float f) {
    __hip_bfloat16 h = __float2bfloat16(f);
    return *reinterpret_cast<unsigned short*>(&h);
}

// ============================================================
// prep: fp32 -> bf16 operand conversion (s, Wcat rows, w_out)
// flat element space: [0,589824) s | [589824,1032192) Wcat | [...,1253376) w_out
// ============================================================
__global__ __launch_bounds__(256) void prep_kernel(
    const float* __restrict__ s,
    const float* __restrict__ w_q,  const float* __restrict__ w_kv,
    const float* __restrict__ w_qp, const float* __restrict__ w_kvp,
    const float* __restrict__ w_out,
    unsigned short* __restrict__ SB, unsigned short* __restrict__ WB,
    unsigned short* __restrict__ WOB)
{
    const long i4 = ((long)blockIdx.x * 256 + threadIdx.x) * 4;
    const float* src; unsigned short* dst; long off;
    if (i4 < 589824) {
        src = s + i4; dst = SB; off = i4;
    } else if (i4 < 1032192) {
        long e = i4 - 589824;
        int row = (int)(e / 384), c = (int)(e - (long)row * 384);
        const float* wsrc;
        if (row < 192)      wsrc = w_q   + (long)row * 384;
        else if (row < 576) wsrc = w_kv  + (long)(row - 192) * 384;
        else if (row < 720) wsrc = w_qp  + (long)(row - 576) * 384;
        else                wsrc = w_kvp + (long)(row - 720) * 384;
        src = wsrc + c; dst = WB; off = e;
    } else {
        long e = i4 - 1032192;
        src = w_out + e; dst = WOB; off = e;
    }
    float4 v = *(const float4*)src;
    short4v o;
    o[0] = (short)f2b(v.x); o[1] = (short)f2b(v.y);
    o[2] = (short)f2b(v.z); o[3] = (short)f2b(v.w);
    *(short4v*)(dst + off) = o;
}

// ============================================================
// fused: projection GEMM (MFMA, bf16 operands, blocks 0..1727)
//      + mask-bias pack (blocks 1728..2879)
// ============================================================
__global__ __launch_bounds__(64) void proj_mb_kernel(
    const unsigned short* __restrict__ SB, const unsigned short* __restrict__ WB,
    const float* __restrict__ b_q,  const float* __restrict__ b_kv,
    const float* __restrict__ b_qp, const float* __restrict__ b_kvp,
    const float* __restrict__ mask,
    float* __restrict__ proj, unsigned short* __restrict__ MB)
{
    if (blockIdx.x >= 1728) {
        // ---- mask-bias pack ----
        const int tile = blockIdx.x - 1728;   // b*576 + it*24 + jt
        const int jt = tile % 24;
        const int it = (tile / 24) % 24;
        const int b  = tile / 576;
        const int tt = threadIdx.x;           // == l
        const int i0 = it * 32, j0 = jt * 32;
        const float* mrow = mask + ((long)b * N_ + i0 + (tt & 31)) * N_
                          + j0 + (tt >> 5) * 4;
        union { unsigned short u[16]; short8 v[2]; } o;
        #pragma unroll
        for (int g = 0; g < 4; ++g) {         // j-groups 0,8,16,24
            float4 mv = *(const float4*)(mrow + 8 * g);
            o.u[g*4+0] = f2b(INF_ * (mv.x - 1.f));
            o.u[g*4+1] = f2b(INF_ * (mv.y - 1.f));
            o.u[g*4+2] = f2b(INF_ * (mv.z - 1.f));
            o.u[g*4+3] = f2b(INF_ * (mv.w - 1.f));
        }
        unsigned short* outp = MB + (long)tile * 1024 + tt * 16;
        *(short8*)(outp)     = o.v[0];
        *(short8*)(outp + 8) = o.v[1];
        return;
    }
    // ---- projection GEMM ----
    const int tile = blockIdx.x;          // 48 * 36
    const int tn = tile % 36, tm = tile / 36;
    const int r0 = tm * 32, c0 = tn * 32;
    const int l  = threadIdx.x;
    const int li = l & 31, hf = l >> 5;

    const unsigned short* ap = SB + (long)(r0 + li) * CN_ + hf * 8;
    const int col = c0 + li;
    const unsigned short* wb = WB + (long)col * CN_ + hf * 8;
    const float bias = (col < 192) ? b_q[col] : (col < 576) ? b_kv[col - 192]
                     : (col < 720) ? b_qp[col - 576] : b_kvp[col - 720];

    f32x16 acc = {};
    for (int k = 0; k < CN_; k += 32) {
        short8 a0 = *(const short8*)(ap + k);
        short8 a1 = *(const short8*)(ap + k + 16);
        short8 b0 = *(const short8*)(wb + k);
        short8 b1 = *(const short8*)(wb + k + 16);
        acc = __builtin_amdgcn_mfma_f32_32x32x16_bf16(a0, b0, acc, 0, 0, 0);
        acc = __builtin_amdgcn_mfma_f32_32x32x16_bf16(a1, b1, acc, 0, 0, 0);
    }
    #pragma unroll
    for (int r = 0; r < 16; ++r) {
        int row = r0 + (r & 3) + 8 * (r >> 2) + 4 * hf;
        proj[(long)row * 1152 + col] = acc[r] + bias;
    }
}

// ============================================================
// pack2: rotate/translate + scales -> bf16 frag-ready buffers
// Qf slots: [0:16) q/sqrt48, [16:28) hw*qp, 28=1, 29=1, 30,31=0
// Kf slots: [0:16) k, [16:28) kp, 28=kc_hi, 29=kc_lo, 30,31=0
// Vt[bh][d][n]: d 0..15 = v, 16..39 = vp  (40..63 left unwritten)
// ============================================================
__global__ __launch_bounds__(256) void pack2_kernel(
    const float* __restrict__ proj,
    const float* __restrict__ rot, const float* __restrict__ trans,
    const float* __restrict__ head_weights,
    unsigned short* __restrict__ Qf, unsigned short* __restrict__ Kf,
    unsigned short* __restrict__ Vt)
{
    __shared__ float raw[1152];
    __shared__ float pk[1152];
    __shared__ float rt[12];
    __shared__ float hws[12];
    __shared__ float kcs[12];
    const int bn = blockIdx.x;
    const int t  = threadIdx.x;
    const float* rowg = proj + (long)bn * 1152;
    for (int d = t; d < 288; d += 256)
        ((float4*)raw)[d] = ((const float4*)rowg)[d];
    if (t < 9) rt[t]     = rot[bn * 9 + t];
    if (t < 3) rt[9 + t] = trans[bn * 3 + t];
    if (t < 12) {
        float v  = head_weights[t];
        float sp = (v > 20.f) ? v : log1pf(expf(v));
        hws[t] = sp * 0.13608276348795434f;  // softplus * sqrt(1/54)
    }
    __syncthreads();
    // per-head layout: h*96 + [0:16)q [16:28)qp*hw [28:44)k [44:56)kp [56:72)v [72:96)vp
    for (int slot = t; slot < 1152; slot += 256) {
        int hh = slot / 96, o = slot - hh * 96;
        float val;
        if (o < 16) {
            val = raw[hh * 16 + o] * 0.144337567297406f;  // 1/sqrt(48)
        } else if (o < 28) {
            int c = o - 16, p = c / 3, x = c - p * 3;
            float r0 = raw[576 +      hh * 4 + p];
            float r1 = raw[576 + 48 + hh * 4 + p];
            float r2 = raw[576 + 96 + hh * 4 + p];
            val = (rt[x*3]*r0 + rt[x*3+1]*r1 + rt[x*3+2]*r2 + rt[9+x]) * hws[hh];
        } else if (o < 44) {
            val = raw[192 + hh * 32 + (o - 28)];
        } else if (o < 56) {
            int c = o - 44, p = c / 3, x = c - p * 3;
            float r0 = raw[720 +       hh * 12 + p];
            float r1 = raw[720 + 144 + hh * 12 + p];
            float r2 = raw[720 + 288 + hh * 12 + p];
            val = rt[x*3]*r0 + rt[x*3+1]*r1 + rt[x*3+2]*r2 + rt[9+x];
        } else if (o < 72) {
            val = raw[192 + hh * 32 + 16 + (o - 56)];
        } else {
            int c = o - 72, p = c / 3, x = c - p * 3;
            float r0 = raw[720 +       hh * 12 + 4 + p];
            float r1 = raw[720 + 144 + hh * 12 + 4 + p];
            float r2 = raw[720 + 288 + hh * 12 + 4 + p];
            val = rt[x*3]*r0 + rt[x*3+1]*r1 + rt[x*3+2]*r2 + rt[9+x];
        }
        pk[slot] = val;
    }
    __syncthreads();
    if (t < 12) {
        float s2 = 0.f;
        #pragma unroll
        for (int e = 0; e < 12; ++e) { float v = pk[t * 96 + 44 + e]; s2 += v * v; }
        kcs[t] = -0.5f * hws[t] * s2;
    }
    __syncthreads();
    const int b = bn / N_, n = bn % N_;
    for (int d = t; d < 384; d += 256) {
        int hh = d >> 5, slot = d & 31;
        long base = ((long)(b * H_ + hh) * N_ + n) * 32 + slot;
        float qv, kv;
        if (slot < 28)      qv = pk[hh * 96 + slot];
        else if (slot < 30) qv = 1.f;
        else                qv = 0.f;
        if (slot < 16)      kv = pk[hh * 96 + 28 + slot];
        else if (slot < 28) kv = pk[hh * 96 + 44 + (slot - 16)];
        else if (slot == 28) kv = b2f(f2b(kcs[hh]));
        else if (slot == 29) kv = kcs[hh] - b2f(f2b(kcs[hh]));
        else                kv = 0.f;
        Qf[base] = f2b(qv);
        Kf[base] = f2b(kv);
    }
    for (int d = t; d < 480; d += 256) {
        int hh = d / 40, dd = d - hh * 40;
        Vt[((long)(b * H_ + hh) * 64 + dd) * N_ + n] = f2b(pk[hh * 96 + 56 + dd]);
    }
}

// ============================================================
// MFMA flash attention. Grid (b*12+h)*24+it, 512 threads = 8 waves.
// Wave w sweeps j in [w*96, w*96+96). No LDS in main loop; merge at end.
// ============================================================
__global__ __launch_bounds__(512) void attn2_kernel(
    const unsigned short* __restrict__ Qf, const unsigned short* __restrict__ Kf,
    const unsigned short* __restrict__ Vt, const unsigned short* __restrict__ MB,
    unsigned short* __restrict__ Og, unsigned short* __restrict__ OPg)
{
    __shared__ float red[8][64][22];
    const int blk = blockIdx.x;
    const int it = blk % 24;
    const int bh = blk / 24;
    const int hh = bh % 12;
    const int b  = bh / 12;
    const int t  = threadIdx.x;
    const int w  = t >> 6;
    const int l  = t & 63;
    const int li = l & 31;
    const int hf = l >> 5;
    const int i0 = it * 32;

    const unsigned short* qbase = Qf + ((long)bh * N_ + i0 + li) * 32 + hf * 8;
    short8 q0 = *(const short8*)(qbase);
    short8 q1 = *(const short8*)(qbase + 16);

    f32x16 acc0 = {};
    f32x16 acc1 = {};
    float m = -1e30f, lsum = 0.f;
    const unsigned short* vtb = Vt + (long)bh * 64 * N_;
    const unsigned short* mbb = MB + ((long)(b * 24 + it)) * 24 * 1024;

    for (int jt = w * 3; jt < w * 3 + 3; ++jt) {
        const int j0 = jt * 32;
        // C-init from mask-bias fragments
        const unsigned short* mbp = mbb + (long)jt * 1024 + l * 16;
        short8 mb0 = *(const short8*)(mbp);
        short8 mb1 = *(const short8*)(mbp + 8);
        f32x16 S;
        #pragma unroll
        for (int r = 0; r < 8; ++r) S[r]     = b2f((unsigned short)mb0[r]);
        #pragma unroll
        for (int r = 0; r < 8; ++r) S[8 + r] = b2f((unsigned short)mb1[r]);
        // K fragments (lane: j=li, k chunk hf*8; chunks k0..15 / k16..31)
        const unsigned short* kp = Kf + ((long)bh * N_ + j0 + li) * 32 + hf * 8;
        short8 k0 = *(const short8*)(kp);
        short8 k1 = *(const short8*)(kp + 16);
        // S^T[j][i] = sum_k K[j][k] Q[i][k]  (lane holds col i=li, 16 j rows)
        S = __builtin_amdgcn_mfma_f32_32x32x16_bf16(k0, q0, S, 0, 0, 0);
        S = __builtin_amdgcn_mfma_f32_32x32x16_bf16(k1, q1, S, 0, 0, 0);
        // online softmax for row i=li; halves exchange via permlane32_swap.
        float mloc = S[0];
        #pragma unroll
        for (int r = 1; r < 16; ++r) mloc = fmaxf(mloc, S[r]);
        {
            auto mm = __builtin_amdgcn_permlane32_swap(
                __float_as_int(mloc), __float_as_int(mloc), false, false);
            mloc = fmaxf(__int_as_float(mm[0]), __int_as_float(mm[1]));
        }
        float newm = fmaxf(m, mloc);
        float scale = __expf(m - newm);
        float ps = 0.f;
        f32x16 p;
        #pragma unroll
        for (int r = 0; r < 16; ++r) { p[r] = __expf(S[r] - newm); ps += p[r]; }
        {
            auto ss = __builtin_amdgcn_permlane32_swap(
                __float_as_int(ps), __float_as_int(ps), false, false);
            ps = __int_as_float(ss[0]) + __int_as_float(ss[1]);
        }
        lsum = lsum * scale + ps;
        m = newm;
        #pragma unroll
        for (int r = 0; r < 16; ++r) acc0[r] *= scale;
        #pragma unroll
        for (int r = 0; r < 4; ++r)  acc1[r] *= scale;
        // pack p -> PV B-fragments: lane's own cvt_pk words, in order.
        int c[8];
        #pragma unroll
        for (int r = 0; r < 8; ++r) {
            asm("v_cvt_pk_bf16_f32 %0, %1, %2" : "=v"(c[r]) : "v"(p[2*r]), "v"(p[2*r+1]));
        }
        union { int w4[4]; short8 v; } bf0, bf1;
        bf0.w4[0] = c[0]; bf0.w4[1] = c[1]; bf0.w4[2] = c[2]; bf0.w4[3] = c[3];
        bf1.w4[0] = c[4]; bf1.w4[1] = c[5]; bf1.w4[2] = c[6]; bf1.w4[3] = c[7];
        // V^T A-frags at the matching interleaved j offsets (two 8B loads each)
        union { short4v h[2]; short8 v; } v00, v01, v10, v11;
        const unsigned short* vr0 = vtb + (long)li * N_        + j0 + hf * 4;
        const unsigned short* vr1 = vtb + (long)(32 + li) * N_ + j0 + hf * 4;
        v00.h[0] = *(const short4v*)(vr0);       v00.h[1] = *(const short4v*)(vr0 + 8);
        v01.h[0] = *(const short4v*)(vr1);       v01.h[1] = *(const short4v*)(vr1 + 8);
        v10.h[0] = *(const short4v*)(vr0 + 16);  v10.h[1] = *(const short4v*)(vr0 + 24);
        v11.h[0] = *(const short4v*)(vr1 + 16);  v11.h[1] = *(const short4v*)(vr1 + 24);
        acc0 = __builtin_amdgcn_mfma_f32_32x32x16_bf16(v00.v, bf0.v, acc0, 0, 0, 0);
        acc1 = __builtin_amdgcn_mfma_f32_32x32x16_bf16(v01.v, bf0.v, acc1, 0, 0, 0);
        acc0 = __builtin_amdgcn_mfma_f32_32x32x16_bf16(v10.v, bf1.v, acc0, 0, 0, 0);
        acc1 = __builtin_amdgcn_mfma_f32_32x32x16_bf16(v11.v, bf1.v, acc1, 0, 0, 0);
    }
    // per-wave partials -> LDS
    float* rd = &red[w][l][0];
    rd[0] = m; rd[1] = lsum;
    #pragma unroll
    for (int r = 0; r < 16; ++r) rd[2 + r]  = acc0[r];
    #pragma unroll
    for (int r = 0; r < 4; ++r)  rd[18 + r] = acc1[r];
    __syncthreads();
    // merge 8 chunks: thread group g=t>>6 handles regs {g, g+8, g+16} of slot l2
    {
        const int l2 = t & 63, g = t >> 6;
        const int li2 = l2 & 31, hf2 = l2 >> 5;
        float ms = -1e30f;
        #pragma unroll
        for (int ww = 0; ww < 8; ++ww) ms = fmaxf(ms, red[ww][l2][0]);
        float wt[8]; float lf = 0.f;
        #pragma unroll
        for (int ww = 0; ww < 8; ++ww) {
            wt[ww] = __expf(red[ww][l2][0] - ms);
            lf += wt[ww] * red[ww][l2][1];
        }
        float inv = 1.f / lf;
        const int n = i0 + li2;
        #pragma unroll
        for (int rr = 0; rr < 3; ++rr) {
            int r = g + rr * 8;
            if (r < 20) {
                float v = 0.f;
                #pragma unroll
                for (int ww = 0; ww < 8; ++ww) v += wt[ww] * red[ww][l2][2 + r];
                v *= inv;
                int d = (r < 16) ? ((r & 3) + 8 * (r >> 2) + 4 * hf2)
                                 : (32 + (r - 16) + 4 * hf2);
                unsigned short ov = f2b(v);
                if (d < 16) Og [((long)(b * N_ + n)) * 192 + hh * 16 + d] = ov;
                else        OPg[((long)(b * N_ + n)) * 288 + hh * 24 + (d - 16)] = ov;
            }
        }
    }
}

// ============================================================
// fused cat-build + output GEMM: one wave per 32x32 out tile (576 blocks).
// cat stored chunk-interleaved in LDS: cat_t[72][32][8] ([col/8][row][col%8])
// -> MFMA A-read is lane-contiguous 16B, conflict-free.
// Phases: A) stage OPg + Og + rot/trans; B) 3072 rotations flat over 64 lanes;
// C) 18x2 MFMA, A from LDS, B = WOB rows from global.
// ============================================================
__global__ __launch_bounds__(64) void out_fused(
    const unsigned short* __restrict__ Og, const unsigned short* __restrict__ OPg,
    const float* __restrict__ rot, const float* __restrict__ trans,
    const unsigned short* __restrict__ WOB, const float* __restrict__ b_out,
    float* __restrict__ out)
{
    __shared__ unsigned short cat_t[72][32][8];
    __shared__ unsigned short op_s[32][288];
    __shared__ float rt_s[32][12];
    const int tile = blockIdx.x;          // 48 * 12
    const int tn = tile % 12, tm = tile / 12;
    const int r0 = tm * 32, c0 = tn * 32;
    const int t  = threadIdx.x;

    // Phase A: stage OPg rows, Og -> cat_t chunks 0..23, rot/trans
    for (int e = t; e < 32 * 36; e += 64) {
        int rr = e / 36, c8 = e - rr * 36;
        *(short8*)&op_s[rr][c8 * 8] = *(const short8*)(OPg + (long)(r0 + rr) * 288 + c8 * 8);
    }
    for (int e = t; e < 32 * 24; e += 64) {
        int rr = e / 24, c8 = e - rr * 24;
        *(short8*)&cat_t[c8][rr][0] = *(const short8*)(Og + (long)(r0 + rr) * 192 + c8 * 8);
    }
    for (int e = t; e < 32 * 9; e += 64) {
        int rr = e / 9, c = e - rr * 9;
        rt_s[rr][c] = rot[(long)(r0 + rr) * 9 + c];
    }
    for (int e = t; e < 32 * 3; e += 64) {
        int rr = e / 3, c = e - rr * 3;
        rt_s[rr][9 + c] = trans[(long)(r0 + rr) * 3 + c];
    }
    __syncthreads();
    // Phase B: rotations (32 rows x 96 points, 48 per thread)
    for (int e = t; e < 3072; e += 64) {
        int rr = e / 96, pt = e - (e / 96) * 96;
        const float* rp = rt_s[rr];
        float g0 = b2f(op_s[rr][pt * 3 + 0]) - rp[9];
        float g1 = b2f(op_s[rr][pt * 3 + 1]) - rp[10];
        float g2 = b2f(op_s[rr][pt * 3 + 2]) - rp[11];
        float l0 = rp[0]*g0 + rp[3]*g1 + rp[6]*g2;
        float l1 = rp[1]*g0 + rp[4]*g1 + rp[7]*g2;
        float l2 = rp[2]*g0 + rp[5]*g1 + rp[8]*g2;
        int c;
        c = 192 + pt; cat_t[c >> 3][rr][c & 7] = f2b(l0);
        c = 288 + pt; cat_t[c >> 3][rr][c & 7] = f2b(l1);
        c = 384 + pt; cat_t[c >> 3][rr][c & 7] = f2b(l2);
        c = 480 + pt; cat_t[c >> 3][rr][c & 7] = f2b(sqrtf(l0*l0 + l1*l1 + l2*l2 + EPS_));
    }
    __syncthreads();
    // Phase C: MFMA GEMM
    const int li = t & 31, hf = t >> 5;
    const unsigned short* wp = WOB + (long)(c0 + li) * 576 + hf * 8;
    f32x16 acc = {};
    for (int k = 0; k < 576; k += 32) {
        short8 a0 = *(const short8*)&cat_t[(k >> 3) + hf][li][0];
        short8 a1 = *(const short8*)&cat_t[(k >> 3) + 2 + hf][li][0];
        short8 b0 = *(const short8*)(wp + k);
        short8 b1 = *(const short8*)(wp + k + 16);
        acc = __builtin_amdgcn_mfma_f32_32x32x16_bf16(a0, b0, acc, 0, 0, 0);
        acc = __builtin_amdgcn_mfma_f32_32x32x16_bf16(a1, b1, acc, 0, 0, 0);
    }
    float bias = b_out[c0 + li];
    #pragma unroll
    for (int r = 0; r < 16; ++r) {
        int row = r0 + (r & 3) + 8 * (r >> 2) + 4 * hf;
        out[(long)row * 384 + c0 + li] = acc[r] + bias;
    }
}

// ============================================================
extern "C" void kernel_launch(void* const* d_in, const int* in_sizes, int n_in,
                              void* d_out, int out_size, void* d_ws, size_t ws_size,
                              hipStream_t stream) {
    const float* s            = (const float*)d_in[0];
    const float* rot          = (const float*)d_in[1];
    const float* trans        = (const float*)d_in[2];
    const float* pair_mask    = (const float*)d_in[3];
    const float* w_q          = (const float*)d_in[4];
    const float* b_q          = (const float*)d_in[5];
    const float* w_kv         = (const float*)d_in[6];
    const float* b_kv         = (const float*)d_in[7];
    const float* w_qp         = (const float*)d_in[8];
    const float* b_qp         = (const float*)d_in[9];
    const float* w_kvp        = (const float*)d_in[10];
    const float* b_kvp        = (const float*)d_in[11];
    const float* head_weights = (const float*)d_in[12];
    const float* w_out        = (const float*)d_in[13];
    const float* b_out        = (const float*)d_in[14];
    float* out = (float*)d_out;
    float* ws  = (float*)d_ws;

    float*          PROJ = ws + OFF_PROJ;
    unsigned short* Og   = (unsigned short*)(ws + OFF_O);
    unsigned short* OPg  = (unsigned short*)(ws + OFF_OP);
    unsigned short* Qf   = (unsigned short*)(ws + OFF_QF);
    unsigned short* Kf   = (unsigned short*)(ws + OFF_KF);
    unsigned short* Vt   = (unsigned short*)(ws + OFF_VT);
    unsigned short* SB   = (unsigned short*)(ws + OFF_SB);
    unsigned short* WB   = (unsigned short*)(ws + OFF_WB);
    unsigned short* WOB  = (unsigned short*)(ws + OFF_WOB);
    unsigned short* MBp  = (unsigned short*)(ws + OFF_MB);

    prep_kernel<<<1224, 256, 0, stream>>>(s, w_q, w_kv, w_qp, w_kvp, w_out,
                                          SB, WB, WOB);
    proj_mb_kernel<<<48 * 36 + B_ * 24 * 24, 64, 0, stream>>>(
        SB, WB, b_q, b_kv, b_qp, b_kvp, pair_mask, PROJ, MBp);
    pack2_kernel<<<B_ * N_, 256, 0, stream>>>(PROJ, rot, trans, head_weights,
                                              Qf, Kf, Vt);
    attn2_kernel<<<B_ * H_ * 24, 512, 0, stream>>>(Qf, Kf, Vt, MBp, Og, OPg);
    out_fused<<<48 * 12, 64, 0, stream>>>(Og, OPg, rot, trans, WOB, b_out, out);
}

// Round 10
// 61.352 us; speedup vs baseline: 1.6612x; 1.6612x over previous
//
#include <hip/hip_runtime.h>
#include <hip/hip_bf16.h>
#include <math.h>

typedef __attribute__((ext_vector_type(4)))  short short4v;
typedef __attribute__((ext_vector_type(8)))  short short8;
typedef __attribute__((ext_vector_type(16))) float f32x16;

#define B_   2
#define N_   768
#define CN_  384
#define H_   12
#define INF_ 100000.0f
#define EPS_ 1e-7f

// ---------------- workspace layout (f32-slot offsets) ----------------
// PROJ f32 [1536][1152]  at 0        (dead after pack2; tail reused)
//   Og  bf16 [1536][192] at 589824
//   OPg bf16 [1536][288] at 737280
//   CATT bf16 [48][72][32][8] at 958464   (chunk-interleaved cat)
// Qf  bf16 [24][768][32]      at 1769472
// Kf  bf16 [24][768][32]      at 2064384
// VtT bf16 [24][24][64][32]   at 2359296  (tile-interleaved; d rows 40..63
//     never written: garbage confined to discarded acc1 regs 4..15)
// SB  bf16 [1536][384]        at 2949120
// WB  bf16 [1152][384]        at 3244032
// WOBT bf16 [12][72][32][8]   at 3465216  (chunk-interleaved w_out)
// MB  bf16 [2][24][24][64][16] at 3575808
#define OFF_PROJ 0
#define OFF_O    589824
#define OFF_OP   737280
#define OFF_CAT  958464
#define OFF_QF   1769472
#define OFF_KF   2064384
#define OFF_VT   2359296
#define OFF_SB   2949120
#define OFF_WB   3244032
#define OFF_WOB  3465216
#define OFF_MB   3575808

__device__ inline float b2f(unsigned short u) {
    union { unsigned int i; float f; } x; x.i = ((unsigned int)u) << 16; return x.f;
}
__device__ inline unsigned short f2b(float f) {
    __hip_bfloat16 h = __float2bfloat16(f);
    return *reinterpret_cast<unsigned short*>(&h);
}

// ============================================================
// prep: fp32 -> bf16 operand conversion (s, Wcat rows, w_out->WOBT interleaved)
// ============================================================
__global__ __launch_bounds__(256) void prep_kernel(
    const float* __restrict__ s,
    const float* __restrict__ w_q,  const float* __restrict__ w_kv,
    const float* __restrict__ w_qp, const float* __restrict__ w_kvp,
    const float* __restrict__ w_out,
    unsigned short* __restrict__ SB, unsigned short* __restrict__ WB,
    unsigned short* __restrict__ WOBT)
{
    const long i4 = ((long)blockIdx.x * 256 + threadIdx.x) * 4;
    const float* src; unsigned short* dst; long off;
    if (i4 < 589824) {
        src = s + i4; dst = SB; off = i4;
    } else if (i4 < 1032192) {
        long e = i4 - 589824;
        int row = (int)(e / 384), c = (int)(e - (long)row * 384);
        const float* wsrc;
        if (row < 192)      wsrc = w_q   + (long)row * 384;
        else if (row < 576) wsrc = w_kv  + (long)(row - 192) * 384;
        else if (row < 720) wsrc = w_qp  + (long)(row - 576) * 384;
        else                wsrc = w_kvp + (long)(row - 720) * 384;
        src = wsrc + c; dst = WB; off = e;
    } else {
        long e = i4 - 1032192;           // element in w_out [384][576]
        int row = (int)(e / 576), c = (int)(e - (long)row * 576);
        src = w_out + e; dst = WOBT;
        off = (((long)(row >> 5) * 72 + (c >> 3)) * 32 + (row & 31)) * 8 + (c & 7);
    }
    float4 v = *(const float4*)src;
    short4v o;
    o[0] = (short)f2b(v.x); o[1] = (short)f2b(v.y);
    o[2] = (short)f2b(v.z); o[3] = (short)f2b(v.w);
    *(short4v*)(dst + off) = o;
}

// ============================================================
// fused: projection GEMM (MFMA, bf16 operands, blocks 0..1727)
//      + mask-bias pack (blocks 1728..2879)
// ============================================================
__global__ __launch_bounds__(64) void proj_mb_kernel(
    const unsigned short* __restrict__ SB, const unsigned short* __restrict__ WB,
    const float* __restrict__ b_q,  const float* __restrict__ b_kv,
    const float* __restrict__ b_qp, const float* __restrict__ b_kvp,
    const float* __restrict__ mask,
    float* __restrict__ proj, unsigned short* __restrict__ MB)
{
    if (blockIdx.x >= 1728) {
        // ---- mask-bias pack ----
        const int tile = blockIdx.x - 1728;   // b*576 + it*24 + jt
        const int jt = tile % 24;
        const int it = (tile / 24) % 24;
        const int b  = tile / 576;
        const int tt = threadIdx.x;           // == l
        const int i0 = it * 32, j0 = jt * 32;
        const float* mrow = mask + ((long)b * N_ + i0 + (tt & 31)) * N_
                          + j0 + (tt >> 5) * 4;
        union { unsigned short u[16]; short8 v[2]; } o;
        #pragma unroll
        for (int g = 0; g < 4; ++g) {         // j-groups 0,8,16,24
            float4 mv = *(const float4*)(mrow + 8 * g);
            o.u[g*4+0] = f2b(INF_ * (mv.x - 1.f));
            o.u[g*4+1] = f2b(INF_ * (mv.y - 1.f));
            o.u[g*4+2] = f2b(INF_ * (mv.z - 1.f));
            o.u[g*4+3] = f2b(INF_ * (mv.w - 1.f));
        }
        unsigned short* outp = MB + (long)tile * 1024 + tt * 16;
        *(short8*)(outp)     = o.v[0];
        *(short8*)(outp + 8) = o.v[1];
        return;
    }
    // ---- projection GEMM ----
    const int tile = blockIdx.x;          // 48 * 36
    const int tn = tile % 36, tm = tile / 36;
    const int r0 = tm * 32, c0 = tn * 32;
    const int l  = threadIdx.x;
    const int li = l & 31, hf = l >> 5;

    const unsigned short* ap = SB + (long)(r0 + li) * CN_ + hf * 8;
    const int col = c0 + li;
    const unsigned short* wb = WB + (long)col * CN_ + hf * 8;
    const float bias = (col < 192) ? b_q[col] : (col < 576) ? b_kv[col - 192]
                     : (col < 720) ? b_qp[col - 576] : b_kvp[col - 720];

    f32x16 acc = {};
    for (int k = 0; k < CN_; k += 32) {
        short8 a0 = *(const short8*)(ap + k);
        short8 a1 = *(const short8*)(ap + k + 16);
        short8 b0 = *(const short8*)(wb + k);
        short8 b1 = *(const short8*)(wb + k + 16);
        acc = __builtin_amdgcn_mfma_f32_32x32x16_bf16(a0, b0, acc, 0, 0, 0);
        acc = __builtin_amdgcn_mfma_f32_32x32x16_bf16(a1, b1, acc, 0, 0, 0);
    }
    #pragma unroll
    for (int r = 0; r < 16; ++r) {
        int row = r0 + (r & 3) + 8 * (r >> 2) + 4 * hf;
        proj[(long)row * 1152 + col] = acc[r] + bias;
    }
}

// ============================================================
// pack2: rotate/translate + scales -> bf16 frag-ready buffers
// Qf slots: [0:16) q/sqrt48, [16:28) hw*qp, 28=1, 29=1, 30,31=0
// Kf slots: [0:16) k, [16:28) kp, 28=kc_hi, 29=kc_lo, 30,31=0
// VtT[bh][jt][d][jn]: d 0..15 = v, 16..39 = vp  (40..63 left unwritten)
// ============================================================
__global__ __launch_bounds__(256) void pack2_kernel(
    const float* __restrict__ proj,
    const float* __restrict__ rot, const float* __restrict__ trans,
    const float* __restrict__ head_weights,
    unsigned short* __restrict__ Qf, unsigned short* __restrict__ Kf,
    unsigned short* __restrict__ Vt)
{
    __shared__ float raw[1152];
    __shared__ float pk[1152];
    __shared__ float rt[12];
    __shared__ float hws[12];
    __shared__ float kcs[12];
    const int bn = blockIdx.x;
    const int t  = threadIdx.x;
    const float* rowg = proj + (long)bn * 1152;
    for (int d = t; d < 288; d += 256)
        ((float4*)raw)[d] = ((const float4*)rowg)[d];
    if (t < 9) rt[t]     = rot[bn * 9 + t];
    if (t < 3) rt[9 + t] = trans[bn * 3 + t];
    if (t < 12) {
        float v  = head_weights[t];
        float sp = (v > 20.f) ? v : log1pf(expf(v));
        hws[t] = sp * 0.13608276348795434f;  // softplus * sqrt(1/54)
    }
    __syncthreads();
    // per-head layout: h*96 + [0:16)q [16:28)qp*hw [28:44)k [44:56)kp [56:72)v [72:96)vp
    for (int slot = t; slot < 1152; slot += 256) {
        int hh = slot / 96, o = slot - hh * 96;
        float val;
        if (o < 16) {
            val = raw[hh * 16 + o] * 0.144337567297406f;  // 1/sqrt(48)
        } else if (o < 28) {
            int c = o - 16, p = c / 3, x = c - p * 3;
            float r0 = raw[576 +      hh * 4 + p];
            float r1 = raw[576 + 48 + hh * 4 + p];
            float r2 = raw[576 + 96 + hh * 4 + p];
            val = (rt[x*3]*r0 + rt[x*3+1]*r1 + rt[x*3+2]*r2 + rt[9+x]) * hws[hh];
        } else if (o < 44) {
            val = raw[192 + hh * 32 + (o - 28)];
        } else if (o < 56) {
            int c = o - 44, p = c / 3, x = c - p * 3;
            float r0 = raw[720 +       hh * 12 + p];
            float r1 = raw[720 + 144 + hh * 12 + p];
            float r2 = raw[720 + 288 + hh * 12 + p];
            val = rt[x*3]*r0 + rt[x*3+1]*r1 + rt[x*3+2]*r2 + rt[9+x];
        } else if (o < 72) {
            val = raw[192 + hh * 32 + 16 + (o - 56)];
        } else {
            int c = o - 72, p = c / 3, x = c - p * 3;
            float r0 = raw[720 +       hh * 12 + 4 + p];
            float r1 = raw[720 + 144 + hh * 12 + 4 + p];
            float r2 = raw[720 + 288 + hh * 12 + 4 + p];
            val = rt[x*3]*r0 + rt[x*3+1]*r1 + rt[x*3+2]*r2 + rt[9+x];
        }
        pk[slot] = val;
    }
    __syncthreads();
    if (t < 12) {
        float s2 = 0.f;
        #pragma unroll
        for (int e = 0; e < 12; ++e) { float v = pk[t * 96 + 44 + e]; s2 += v * v; }
        kcs[t] = -0.5f * hws[t] * s2;
    }
    __syncthreads();
    const int b = bn / N_, n = bn % N_;
    for (int d = t; d < 384; d += 256) {
        int hh = d >> 5, slot = d & 31;
        long base = ((long)(b * H_ + hh) * N_ + n) * 32 + slot;
        float qv, kv;
        if (slot < 28)      qv = pk[hh * 96 + slot];
        else if (slot < 30) qv = 1.f;
        else                qv = 0.f;
        if (slot < 16)      kv = pk[hh * 96 + 28 + slot];
        else if (slot < 28) kv = pk[hh * 96 + 44 + (slot - 16)];
        else if (slot == 28) kv = b2f(f2b(kcs[hh]));
        else if (slot == 29) kv = kcs[hh] - b2f(f2b(kcs[hh]));
        else                kv = 0.f;
        Qf[base] = f2b(qv);
        Kf[base] = f2b(kv);
    }
    for (int d = t; d < 480; d += 256) {
        int hh = d / 40, dd = d - hh * 40;
        // VtT[(b*12+hh)][n>>5][dd][n&31]
        Vt[(((long)(b * H_ + hh) * 24 + (n >> 5)) * 64 + dd) * 32 + (n & 31)]
            = f2b(pk[hh * 96 + 56 + dd]);
    }
}

// ============================================================
// MFMA flash attention. Grid (b*12+h)*24+it, 512 threads = 8 waves.
// Wave w sweeps j in [w*96, w*96+96). No LDS in main loop; merge at end.
// VtT d-rows 40..63 uninitialized: feed only discarded acc1 regs 4..15.
// ============================================================
__global__ __launch_bounds__(512) void attn2_kernel(
    const unsigned short* __restrict__ Qf, const unsigned short* __restrict__ Kf,
    const unsigned short* __restrict__ Vt, const unsigned short* __restrict__ MB,
    unsigned short* __restrict__ Og, unsigned short* __restrict__ OPg)
{
    __shared__ float red[8][64][23];   // 23: odd stride -> conflict-free merge
    const int blk = blockIdx.x;
    const int it = blk % 24;
    const int bh = blk / 24;
    const int hh = bh % 12;
    const int b  = bh / 12;
    const int t  = threadIdx.x;
    const int w  = t >> 6;
    const int l  = t & 63;
    const int li = l & 31;
    const int hf = l >> 5;
    const int i0 = it * 32;

    const unsigned short* qbase = Qf + ((long)bh * N_ + i0 + li) * 32 + hf * 8;
    short8 q0 = *(const short8*)(qbase);
    short8 q1 = *(const short8*)(qbase + 16);

    f32x16 acc0 = {};
    f32x16 acc1 = {};
    float m = -1e30f, lsum = 0.f;
    const unsigned short* vtb = Vt + (long)bh * 24 * 2048;   // per-bh tile base
    const unsigned short* mbb = MB + ((long)(b * 24 + it)) * 24 * 1024;

    for (int jt = w * 3; jt < w * 3 + 3; ++jt) {
        const int j0 = jt * 32;
        // C-init from mask-bias fragments
        const unsigned short* mbp = mbb + (long)jt * 1024 + l * 16;
        short8 mb0 = *(const short8*)(mbp);
        short8 mb1 = *(const short8*)(mbp + 8);
        f32x16 S;
        #pragma unroll
        for (int r = 0; r < 8; ++r) S[r]     = b2f((unsigned short)mb0[r]);
        #pragma unroll
        for (int r = 0; r < 8; ++r) S[8 + r] = b2f((unsigned short)mb1[r]);
        // K fragments (lane: j=li, k chunk hf*8; chunks k0..15 / k16..31)
        const unsigned short* kp = Kf + ((long)bh * N_ + j0 + li) * 32 + hf * 8;
        short8 k0 = *(const short8*)(kp);
        short8 k1 = *(const short8*)(kp + 16);
        // S^T[j][i] = sum_k K[j][k] Q[i][k]  (lane holds col i=li, 16 j rows)
        S = __builtin_amdgcn_mfma_f32_32x32x16_bf16(k0, q0, S, 0, 0, 0);
        S = __builtin_amdgcn_mfma_f32_32x32x16_bf16(k1, q1, S, 0, 0, 0);
        // online softmax for row i=li; halves exchange via permlane32_swap.
        float mloc = S[0];
        #pragma unroll
        for (int r = 1; r < 16; ++r) mloc = fmaxf(mloc, S[r]);
        {
            auto mm = __builtin_amdgcn_permlane32_swap(
                __float_as_int(mloc), __float_as_int(mloc), false, false);
            mloc = fmaxf(__int_as_float(mm[0]), __int_as_float(mm[1]));
        }
        float newm = fmaxf(m, mloc);
        float scale = __expf(m - newm);
        float ps = 0.f;
        f32x16 p;
        #pragma unroll
        for (int r = 0; r < 16; ++r) { p[r] = __expf(S[r] - newm); ps += p[r]; }
        {
            auto ss = __builtin_amdgcn_permlane32_swap(
                __float_as_int(ps), __float_as_int(ps), false, false);
            ps = __int_as_float(ss[0]) + __int_as_float(ss[1]);
        }
        lsum = lsum * scale + ps;
        m = newm;
        #pragma unroll
        for (int r = 0; r < 16; ++r) acc0[r] *= scale;
        #pragma unroll
        for (int r = 0; r < 4; ++r)  acc1[r] *= scale;
        // pack p -> PV B-fragments: lane's own cvt_pk words, in order.
        int c[8];
        #pragma unroll
        for (int r = 0; r < 8; ++r) {
            asm("v_cvt_pk_bf16_f32 %0, %1, %2" : "=v"(c[r]) : "v"(p[2*r]), "v"(p[2*r+1]));
        }
        union { int w4[4]; short8 v; } bf0, bf1;
        bf0.w4[0] = c[0]; bf0.w4[1] = c[1]; bf0.w4[2] = c[2]; bf0.w4[3] = c[3];
        bf1.w4[0] = c[4]; bf1.w4[1] = c[5]; bf1.w4[2] = c[6]; bf1.w4[3] = c[7];
        // V^T A-frags, tile-interleaved: lane (li,hf) reads contiguous 8B runs
        const unsigned short* tb  = vtb + jt * 2048;
        const unsigned short* vr0 = tb + li * 32 + hf * 4;
        const unsigned short* vr1 = tb + (32 + li) * 32 + hf * 4;
        union { short4v h[2]; short8 v; } v00, v01, v10, v11;
        v00.h[0] = *(const short4v*)(vr0);       v00.h[1] = *(const short4v*)(vr0 + 8);
        v01.h[0] = *(const short4v*)(vr1);       v01.h[1] = *(const short4v*)(vr1 + 8);
        v10.h[0] = *(const short4v*)(vr0 + 16);  v10.h[1] = *(const short4v*)(vr0 + 24);
        v11.h[0] = *(const short4v*)(vr1 + 16);  v11.h[1] = *(const short4v*)(vr1 + 24);
        acc0 = __builtin_amdgcn_mfma_f32_32x32x16_bf16(v00.v, bf0.v, acc0, 0, 0, 0);
        acc1 = __builtin_amdgcn_mfma_f32_32x32x16_bf16(v01.v, bf0.v, acc1, 0, 0, 0);
        acc0 = __builtin_amdgcn_mfma_f32_32x32x16_bf16(v10.v, bf1.v, acc0, 0, 0, 0);
        acc1 = __builtin_amdgcn_mfma_f32_32x32x16_bf16(v11.v, bf1.v, acc1, 0, 0, 0);
    }
    // per-wave partials -> LDS
    float* rd = &red[w][l][0];
    rd[0] = m; rd[1] = lsum;
    #pragma unroll
    for (int r = 0; r < 16; ++r) rd[2 + r]  = acc0[r];
    #pragma unroll
    for (int r = 0; r < 4; ++r)  rd[18 + r] = acc1[r];
    __syncthreads();
    // merge 8 chunks: thread group g=t>>6 handles regs {g, g+8, g+16} of slot l2
    {
        const int l2 = t & 63, g = t >> 6;
        const int li2 = l2 & 31, hf2 = l2 >> 5;
        float ms = -1e30f;
        #pragma unroll
        for (int ww = 0; ww < 8; ++ww) ms = fmaxf(ms, red[ww][l2][0]);
        float wt[8]; float lf = 0.f;
        #pragma unroll
        for (int ww = 0; ww < 8; ++ww) {
            wt[ww] = __expf(red[ww][l2][0] - ms);
            lf += wt[ww] * red[ww][l2][1];
        }
        float inv = 1.f / lf;
        const int n = i0 + li2;
        #pragma unroll
        for (int rr = 0; rr < 3; ++rr) {
            int r = g + rr * 8;
            if (r < 20) {
                float v = 0.f;
                #pragma unroll
                for (int ww = 0; ww < 8; ++ww) v += wt[ww] * red[ww][l2][2 + r];
                v *= inv;
                int d = (r < 16) ? ((r & 3) + 8 * (r >> 2) + 4 * hf2)
                                 : (32 + (r - 16) + 4 * hf2);
                unsigned short ov = f2b(v);
                if (d < 16) Og [((long)(b * N_ + n)) * 192 + hh * 16 + d] = ov;
                else        OPg[((long)(b * N_ + n)) * 288 + hh * 24 + (d - 16)] = ov;
            }
        }
    }
}

// ============================================================
// cat build: inverse rotation + norms -> CATT[48][72][32][8] (chunk-interleaved)
// ============================================================
__global__ __launch_bounds__(128) void cat_kernel(
    const unsigned short* __restrict__ Og, const unsigned short* __restrict__ OPg,
    const float* __restrict__ rot, const float* __restrict__ trans,
    unsigned short* __restrict__ catgT)
{
    __shared__ float cat[576];
    __shared__ float rt[12];
    const int bn = blockIdx.x;
    const int t  = threadIdx.x;
    if (t < 9) rt[t]     = rot[bn * 9 + t];
    if (t < 3) rt[9 + t] = trans[bn * 3 + t];
    for (int d = t; d < 192; d += 128) cat[d] = b2f(Og[(long)bn * 192 + d]);
    __syncthreads();
    if (t < 96) {
        float g0 = b2f(OPg[(long)bn * 288 + t * 3 + 0]) - rt[9];
        float g1 = b2f(OPg[(long)bn * 288 + t * 3 + 1]) - rt[10];
        float g2 = b2f(OPg[(long)bn * 288 + t * 3 + 2]) - rt[11];
        float l0 = rt[0]*g0 + rt[3]*g1 + rt[6]*g2;
        float l1 = rt[1]*g0 + rt[4]*g1 + rt[7]*g2;
        float l2 = rt[2]*g0 + rt[5]*g1 + rt[8]*g2;
        cat[192 + t] = l0;
        cat[288 + t] = l1;
        cat[384 + t] = l2;
        cat[480 + t] = sqrtf(l0*l0 + l1*l1 + l2*l2 + EPS_);
    }
    __syncthreads();
    const long sbase = ((long)(bn >> 5)) * 72 * 256 + (bn & 31) * 8;
    for (int d = t; d < 576; d += 128)
        catgT[sbase + (long)(d >> 3) * 256 + (d & 7)] = f2b(cat[d]);
}

// ============================================================
// output GEMM (MFMA, interleaved operands): out = cat @ w_out^T + b_out
// one wave per 32x32 tile; A/B reads are lane-contiguous 512B runs.
// ============================================================
__global__ __launch_bounds__(64) void out_mfma(
    const unsigned short* __restrict__ catgT,  // [48][72][32][8]
    const unsigned short* __restrict__ WOBT,   // [12][72][32][8]
    const float* __restrict__ b_out,
    float* __restrict__ out)
{
    const int tile = blockIdx.x;          // 48 * 12
    const int tn = tile % 12, tm = tile / 12;
    const int r0 = tm * 32, c0 = tn * 32;
    const int l  = threadIdx.x;
    const int li = l & 31, hf = l >> 5;

    const unsigned short* ab = catgT + (long)tm * 72 * 256;
    const unsigned short* wb = WOBT  + (long)tn * 72 * 256;

    f32x16 acc = {};
    for (int k = 0; k < 576; k += 32) {
        const int c = (k >> 3) + hf;
        short8 a0 = *(const short8*)(ab + (c * 32 + li) * 8);
        short8 a1 = *(const short8*)(ab + ((c + 2) * 32 + li) * 8);
        short8 b0 = *(const short8*)(wb + (c * 32 + li) * 8);
        short8 b1 = *(const short8*)(wb + ((c + 2) * 32 + li) * 8);
        acc = __builtin_amdgcn_mfma_f32_32x32x16_bf16(a0, b0, acc, 0, 0, 0);
        acc = __builtin_amdgcn_mfma_f32_32x32x16_bf16(a1, b1, acc, 0, 0, 0);
    }
    float bias = b_out[c0 + li];
    #pragma unroll
    for (int r = 0; r < 16; ++r) {
        int row = r0 + (r & 3) + 8 * (r >> 2) + 4 * hf;
        out[(long)row * 384 + c0 + li] = acc[r] + bias;
    }
}

// ============================================================
extern "C" void kernel_launch(void* const* d_in, const int* in_sizes, int n_in,
                              void* d_out, int out_size, void* d_ws, size_t ws_size,
                              hipStream_t stream) {
    const float* s            = (const float*)d_in[0];
    const float* rot          = (const float*)d_in[1];
    const float* trans        = (const float*)d_in[2];
    const float* pair_mask    = (const float*)d_in[3];
    const float* w_q          = (const float*)d_in[4];
    const float* b_q          = (const float*)d_in[5];
    const float* w_kv         = (const float*)d_in[6];
    const float* b_kv         = (const float*)d_in[7];
    const float* w_qp         = (const float*)d_in[8];
    const float* b_qp         = (const float*)d_in[9];
    const float* w_kvp        = (const float*)d_in[10];
    const float* b_kvp        = (const float*)d_in[11];
    const float* head_weights = (const float*)d_in[12];
    const float* w_out        = (const float*)d_in[13];
    const float* b_out        = (const float*)d_in[14];
    float* out = (float*)d_out;
    float* ws  = (float*)d_ws;

    float*          PROJ = ws + OFF_PROJ;
    unsigned short* Og   = (unsigned short*)(ws + OFF_O);
    unsigned short* OPg  = (unsigned short*)(ws + OFF_OP);
    unsigned short* CATT = (unsigned short*)(ws + OFF_CAT);
    unsigned short* Qf   = (unsigned short*)(ws + OFF_QF);
    unsigned short* Kf   = (unsigned short*)(ws + OFF_KF);
    unsigned short* Vt   = (unsigned short*)(ws + OFF_VT);
    unsigned short* SB   = (unsigned short*)(ws + OFF_SB);
    unsigned short* WB   = (unsigned short*)(ws + OFF_WB);
    unsigned short* WOBT = (unsigned short*)(ws + OFF_WOB);
    unsigned short* MBp  = (unsigned short*)(ws + OFF_MB);

    prep_kernel<<<1224, 256, 0, stream>>>(s, w_q, w_kv, w_qp, w_kvp, w_out,
                                          SB, WB, WOBT);
    proj_mb_kernel<<<48 * 36 + B_ * 24 * 24, 64, 0, stream>>>(
        SB, WB, b_q, b_kv, b_qp, b_kvp, pair_mask, PROJ, MBp);
    pack2_kernel<<<B_ * N_, 256, 0, stream>>>(PROJ, rot, trans, head_weights,
                                              Qf, Kf, Vt);
    attn2_kernel<<<B_ * H_ * 24, 512, 0, stream>>>(Qf, Kf, Vt, MBp, Og, OPg);
    cat_kernel<<<B_ * N_, 128, 0, stream>>>(Og, OPg, rot, trans, CATT);
    out_mfma<<<48 * 12, 64, 0, stream>>>(CATT, WOBT, b_out, out);
}

// Round 11
// 57.692 us; speedup vs baseline: 1.7666x; 1.0634x over previous
//
#include <hip/hip_runtime.h>
#include <hip/hip_bf16.h>
#include <math.h>

typedef __attribute__((ext_vector_type(4)))  short short4v;
typedef __attribute__((ext_vector_type(8)))  short short8;
typedef __attribute__((ext_vector_type(16))) float f32x16;

#define B_   2
#define N_   768
#define CN_  384
#define H_   12
#define INF_ 100000.0f
#define EPS_ 1e-7f

// ---------------- workspace layout (f32-slot offsets) ----------------
// PROJP f32 [1536][576]       at 0        (point-proj columns + bias; dead after pack3)
// Og  bf16 [1536][192]        at 884736
// OPg bf16 [1536][288]        at 1032192
// CATT bf16 [48][72][32][8]   at 1253376  (chunk-interleaved cat)
// Qf  bf16 [24][768][32]      at 1769472
// Kf  bf16 [24][768][32]      at 2064384
// VtT bf16 [24][24][64][32]   at 2359296  (tile-interleaved; d rows 40..63
//     never written: garbage confined to discarded acc1 regs 4..15)
// SB  bf16 [1536][384]        at 2949120
// WB  bf16 [1152][384]        at 3244032
// WOBT bf16 [12][72][32][8]   at 3465216  (chunk-interleaved w_out)
// MB  bf16 [2][24][24][64][16] at 3575808
#define OFF_PROJP 0
#define OFF_O     884736
#define OFF_OP    1032192
#define OFF_CAT   1253376
#define OFF_QF    1769472
#define OFF_KF    2064384
#define OFF_VT    2359296
#define OFF_SB    2949120
#define OFF_WB    3244032
#define OFF_WOB   3465216
#define OFF_MB    3575808

__device__ inline float b2f(unsigned short u) {
    union { unsigned int i; float f; } x; x.i = ((unsigned int)u) << 16; return x.f;
}
__device__ inline unsigned short f2b(float f) {
    __hip_bfloat16 h = __float2bfloat16(f);
    return *reinterpret_cast<unsigned short*>(&h);
}

// ============================================================
// prep: fp32 -> bf16 operand conversion (s, Wcat rows, w_out->WOBT interleaved)
// ============================================================
__global__ __launch_bounds__(256) void prep_kernel(
    const float* __restrict__ s,
    const float* __restrict__ w_q,  const float* __restrict__ w_kv,
    const float* __restrict__ w_qp, const float* __restrict__ w_kvp,
    const float* __restrict__ w_out,
    unsigned short* __restrict__ SB, unsigned short* __restrict__ WB,
    unsigned short* __restrict__ WOBT)
{
    const long i4 = ((long)blockIdx.x * 256 + threadIdx.x) * 4;
    const float* src; unsigned short* dst; long off;
    if (i4 < 589824) {
        src = s + i4; dst = SB; off = i4;
    } else if (i4 < 1032192) {
        long e = i4 - 589824;
        int row = (int)(e / 384), c = (int)(e - (long)row * 384);
        const float* wsrc;
        if (row < 192)      wsrc = w_q   + (long)row * 384;
        else if (row < 576) wsrc = w_kv  + (long)(row - 192) * 384;
        else if (row < 720) wsrc = w_qp  + (long)(row - 576) * 384;
        else                wsrc = w_kvp + (long)(row - 720) * 384;
        src = wsrc + c; dst = WB; off = e;
    } else {
        long e = i4 - 1032192;           // element in w_out [384][576]
        int row = (int)(e / 576), c = (int)(e - (long)row * 576);
        src = w_out + e; dst = WOBT;
        off = (((long)(row >> 5) * 72 + (c >> 3)) * 32 + (row & 31)) * 8 + (c & 7);
    }
    float4 v = *(const float4*)src;
    short4v o;
    o[0] = (short)f2b(v.x); o[1] = (short)f2b(v.y);
    o[2] = (short)f2b(v.z); o[3] = (short)f2b(v.w);
    *(short4v*)(dst + off) = o;
}

// ============================================================
// fused: projection GEMM (MFMA, blocks 0..1727) + mask-bias pack (1728..2879)
// proj epilogue routes by wave-uniform tile type:
//   tn<6   : q cols    -> Qf slots 0..15, (acc+bias)/sqrt48
//   tn<18  : kv cols   -> Kf slots 0..15 (lanes<16) / VtT d 0..15 (lanes>=16);
//            h = tn-6 uniform
//   tn>=18 : point cols -> PROJP[row][col-576] = acc+bias (fp32)
// ============================================================
__global__ __launch_bounds__(64) void proj_mb_kernel(
    const unsigned short* __restrict__ SB, const unsigned short* __restrict__ WB,
    const float* __restrict__ b_q,  const float* __restrict__ b_kv,
    const float* __restrict__ b_qp, const float* __restrict__ b_kvp,
    const float* __restrict__ mask,
    float* __restrict__ PROJP, unsigned short* __restrict__ Qf,
    unsigned short* __restrict__ Kf, unsigned short* __restrict__ Vt,
    unsigned short* __restrict__ MB)
{
    if (blockIdx.x >= 1728) {
        // ---- mask-bias pack ----
        const int tile = blockIdx.x - 1728;   // b*576 + it*24 + jt
        const int jt = tile % 24;
        const int it = (tile / 24) % 24;
        const int b  = tile / 576;
        const int tt = threadIdx.x;           // == l
        const int i0 = it * 32, j0 = jt * 32;
        const float* mrow = mask + ((long)b * N_ + i0 + (tt & 31)) * N_
                          + j0 + (tt >> 5) * 4;
        union { unsigned short u[16]; short8 v[2]; } o;
        #pragma unroll
        for (int g = 0; g < 4; ++g) {         // j-groups 0,8,16,24
            float4 mv = *(const float4*)(mrow + 8 * g);
            o.u[g*4+0] = f2b(INF_ * (mv.x - 1.f));
            o.u[g*4+1] = f2b(INF_ * (mv.y - 1.f));
            o.u[g*4+2] = f2b(INF_ * (mv.z - 1.f));
            o.u[g*4+3] = f2b(INF_ * (mv.w - 1.f));
        }
        unsigned short* outp = MB + (long)tile * 1024 + tt * 16;
        *(short8*)(outp)     = o.v[0];
        *(short8*)(outp + 8) = o.v[1];
        return;
    }
    // ---- projection GEMM ----
    const int tile = blockIdx.x;          // 48 * 36
    const int tn = tile % 36, tm = tile / 36;
    const int r0 = tm * 32, c0 = tn * 32;
    const int l  = threadIdx.x;
    const int li = l & 31, hf = l >> 5;

    const unsigned short* ap = SB + (long)(r0 + li) * CN_ + hf * 8;
    const int col = c0 + li;
    const unsigned short* wb = WB + (long)col * CN_ + hf * 8;
    const float bias = (col < 192) ? b_q[col] : (col < 576) ? b_kv[col - 192]
                     : (col < 720) ? b_qp[col - 576] : b_kvp[col - 720];

    f32x16 acc = {};
    for (int k = 0; k < CN_; k += 32) {
        short8 a0 = *(const short8*)(ap + k);
        short8 a1 = *(const short8*)(ap + k + 16);
        short8 b0 = *(const short8*)(wb + k);
        short8 b1 = *(const short8*)(wb + k + 16);
        acc = __builtin_amdgcn_mfma_f32_32x32x16_bf16(a0, b0, acc, 0, 0, 0);
        acc = __builtin_amdgcn_mfma_f32_32x32x16_bf16(a1, b1, acc, 0, 0, 0);
    }
    const int row_b = r0 / N_;            // uniform: 768 % 32 == 0
    if (tn < 6) {                         // q tile
        const int hq = col >> 4, c = col & 15;
        const long qb = (long)(row_b * H_ + hq) * N_;
        #pragma unroll
        for (int r = 0; r < 16; ++r) {
            int row = r0 + (r & 3) + 8 * (r >> 2) + 4 * hf;
            int n = row - row_b * N_;
            Qf[(qb + n) * 32 + c] = f2b((acc[r] + bias) * 0.144337567297406f);
        }
    } else if (tn < 18) {                 // kv tile, h = tn-6 uniform
        const int hkv = tn - 6;
        const long kb = (long)(row_b * H_ + hkv) * N_;
        const long vb = (long)(row_b * H_ + hkv) * 24;
        #pragma unroll
        for (int r = 0; r < 16; ++r) {
            int row = r0 + (r & 3) + 8 * (r >> 2) + 4 * hf;
            int n = row - row_b * N_;
            unsigned short v = f2b(acc[r] + bias);
            if (li < 16) Kf[(kb + n) * 32 + li] = v;
            else Vt[((vb + (n >> 5)) * 64 + (li - 16)) * 32 + (n & 31)] = v;
        }
    } else {                              // point tile -> PROJP fp32
        const int pc = col - 576;
        #pragma unroll
        for (int r = 0; r < 16; ++r) {
            int row = r0 + (r & 3) + 8 * (r >> 2) + 4 * hf;
            PROJP[(long)row * 576 + pc] = acc[r] + bias;
        }
    }
}

// ============================================================
// pack3: rotations only. One block (128 thr) per (b,n).
// PROJP row layout: [0:144) qp raw [y*48+h*4+p], [144:576) kvp raw [144+y*144+h*12+pp]
// Writes: Qf slots 16..31, Kf slots 16..31, VtT d 16..39.
// ============================================================
__global__ __launch_bounds__(128) void pack3_kernel(
    const float* __restrict__ PROJP,
    const float* __restrict__ rot, const float* __restrict__ trans,
    const float* __restrict__ head_weights,
    unsigned short* __restrict__ Qf, unsigned short* __restrict__ Kf,
    unsigned short* __restrict__ Vt)
{
    __shared__ float pp[576];
    __shared__ float rt[12];
    __shared__ float hws[12];
    __shared__ float kp2[48];
    const int bn = blockIdx.x;
    const int t  = threadIdx.x;
    const float4* src = (const float4*)(PROJP + (long)bn * 576);
    for (int d = t; d < 144; d += 128) ((float4*)pp)[d] = src[d];
    if (t < 9) rt[t]     = rot[bn * 9 + t];
    if (t < 3) rt[9 + t] = trans[bn * 3 + t];
    if (t < 12) {
        float v  = head_weights[t];
        float sp = (v > 20.f) ? v : log1pf(expf(v));
        hws[t] = sp * 0.13608276348795434f;  // softplus * sqrt(1/54)
    }
    __syncthreads();
    const int b = bn / N_, n = bn % N_;
    for (int e = t; e < 192; e += 128) {
        if (e < 48) {                     // qp point (h, p)
            int h = e >> 2, p = e & 3;
            float r0 = pp[     h * 4 + p];
            float r1 = pp[48 + h * 4 + p];
            float r2 = pp[96 + h * 4 + p];
            long base = ((long)(b * H_ + h) * N_ + n) * 32;
            #pragma unroll
            for (int x = 0; x < 3; ++x) {
                float o = rt[x*3]*r0 + rt[x*3+1]*r1 + rt[x*3+2]*r2 + rt[9+x];
                Qf[base + 16 + p * 3 + x] = f2b(o * hws[h]);
            }
        } else {                          // kvp point (h, pp_i)
            int idx = e - 48;
            int h = idx / 12, pi = idx - h * 12;
            float r0 = pp[144 +       h * 12 + pi];
            float r1 = pp[144 + 144 + h * 12 + pi];
            float r2 = pp[144 + 288 + h * 12 + pi];
            float o0 = rt[0]*r0 + rt[1]*r1 + rt[2]*r2 + rt[9];
            float o1 = rt[3]*r0 + rt[4]*r1 + rt[5]*r2 + rt[10];
            float o2 = rt[6]*r0 + rt[7]*r1 + rt[8]*r2 + rt[11];
            if (pi < 4) {
                long base = ((long)(b * H_ + h) * N_ + n) * 32;
                Kf[base + 16 + pi * 3 + 0] = f2b(o0);
                Kf[base + 16 + pi * 3 + 1] = f2b(o1);
                Kf[base + 16 + pi * 3 + 2] = f2b(o2);
                kp2[h * 4 + pi] = o0*o0 + o1*o1 + o2*o2;
            } else {
                int dd = 16 + (pi - 4) * 3;
                long vb = ((long)(b * H_ + h) * 24 + (n >> 5)) * 64;
                Vt[(vb + dd + 0) * 32 + (n & 31)] = f2b(o0);
                Vt[(vb + dd + 1) * 32 + (n & 31)] = f2b(o1);
                Vt[(vb + dd + 2) * 32 + (n & 31)] = f2b(o2);
            }
        }
    }
    __syncthreads();
    if (t < 12) {
        float s2 = kp2[t*4] + kp2[t*4+1] + kp2[t*4+2] + kp2[t*4+3];
        float kc = -0.5f * hws[t] * s2;
        long base = ((long)(b * H_ + t) * N_ + n) * 32;
        unsigned short hi = f2b(kc);
        Kf[base + 28] = hi;
        Kf[base + 29] = f2b(kc - b2f(hi));
        Kf[base + 30] = 0; Kf[base + 31] = 0;
        unsigned short one = f2b(1.f);
        Qf[base + 28] = one; Qf[base + 29] = one;
        Qf[base + 30] = 0;   Qf[base + 31] = 0;
    }
}

// ============================================================
// MFMA flash attention. Grid (b*12+h)*24+it, 512 threads = 8 waves.
// Wave w sweeps j in [w*96, w*96+96). No LDS in main loop; merge at end.
// VtT d-rows 40..63 uninitialized: feed only discarded acc1 regs 4..15.
// ============================================================
__global__ __launch_bounds__(512) void attn2_kernel(
    const unsigned short* __restrict__ Qf, const unsigned short* __restrict__ Kf,
    const unsigned short* __restrict__ Vt, const unsigned short* __restrict__ MB,
    unsigned short* __restrict__ Og, unsigned short* __restrict__ OPg)
{
    __shared__ float red[8][64][23];   // 23: odd stride -> conflict-free merge
    const int blk = blockIdx.x;
    const int it = blk % 24;
    const int bh = blk / 24;
    const int hh = bh % 12;
    const int b  = bh / 12;
    const int t  = threadIdx.x;
    const int w  = t >> 6;
    const int l  = t & 63;
    const int li = l & 31;
    const int hf = l >> 5;
    const int i0 = it * 32;

    const unsigned short* qbase = Qf + ((long)bh * N_ + i0 + li) * 32 + hf * 8;
    short8 q0 = *(const short8*)(qbase);
    short8 q1 = *(const short8*)(qbase + 16);

    f32x16 acc0 = {};
    f32x16 acc1 = {};
    float m = -1e30f, lsum = 0.f;
    const unsigned short* vtb = Vt + (long)bh * 24 * 2048;
    const unsigned short* mbb = MB + ((long)(b * 24 + it)) * 24 * 1024;

    for (int jt = w * 3; jt < w * 3 + 3; ++jt) {
        const int j0 = jt * 32;
        const unsigned short* mbp = mbb + (long)jt * 1024 + l * 16;
        short8 mb0 = *(const short8*)(mbp);
        short8 mb1 = *(const short8*)(mbp + 8);
        f32x16 S;
        #pragma unroll
        for (int r = 0; r < 8; ++r) S[r]     = b2f((unsigned short)mb0[r]);
        #pragma unroll
        for (int r = 0; r < 8; ++r) S[8 + r] = b2f((unsigned short)mb1[r]);
        const unsigned short* kp = Kf + ((long)bh * N_ + j0 + li) * 32 + hf * 8;
        short8 k0 = *(const short8*)(kp);
        short8 k1 = *(const short8*)(kp + 16);
        S = __builtin_amdgcn_mfma_f32_32x32x16_bf16(k0, q0, S, 0, 0, 0);
        S = __builtin_amdgcn_mfma_f32_32x32x16_bf16(k1, q1, S, 0, 0, 0);
        float mloc = S[0];
        #pragma unroll
        for (int r = 1; r < 16; ++r) mloc = fmaxf(mloc, S[r]);
        {
            auto mm = __builtin_amdgcn_permlane32_swap(
                __float_as_int(mloc), __float_as_int(mloc), false, false);
            mloc = fmaxf(__int_as_float(mm[0]), __int_as_float(mm[1]));
        }
        float newm = fmaxf(m, mloc);
        float scale = __expf(m - newm);
        float ps = 0.f;
        f32x16 p;
        #pragma unroll
        for (int r = 0; r < 16; ++r) { p[r] = __expf(S[r] - newm); ps += p[r]; }
        {
            auto ss = __builtin_amdgcn_permlane32_swap(
                __float_as_int(ps), __float_as_int(ps), false, false);
            ps = __int_as_float(ss[0]) + __int_as_float(ss[1]);
        }
        lsum = lsum * scale + ps;
        m = newm;
        #pragma unroll
        for (int r = 0; r < 16; ++r) acc0[r] *= scale;
        #pragma unroll
        for (int r = 0; r < 4; ++r)  acc1[r] *= scale;
        int c[8];
        #pragma unroll
        for (int r = 0; r < 8; ++r) {
            asm("v_cvt_pk_bf16_f32 %0, %1, %2" : "=v"(c[r]) : "v"(p[2*r]), "v"(p[2*r+1]));
        }
        union { int w4[4]; short8 v; } bf0, bf1;
        bf0.w4[0] = c[0]; bf0.w4[1] = c[1]; bf0.w4[2] = c[2]; bf0.w4[3] = c[3];
        bf1.w4[0] = c[4]; bf1.w4[1] = c[5]; bf1.w4[2] = c[6]; bf1.w4[3] = c[7];
        const unsigned short* tb  = vtb + jt * 2048;
        const unsigned short* vr0 = tb + li * 32 + hf * 4;
        const unsigned short* vr1 = tb + (32 + li) * 32 + hf * 4;
        union { short4v h[2]; short8 v; } v00, v01, v10, v11;
        v00.h[0] = *(const short4v*)(vr0);       v00.h[1] = *(const short4v*)(vr0 + 8);
        v01.h[0] = *(const short4v*)(vr1);       v01.h[1] = *(const short4v*)(vr1 + 8);
        v10.h[0] = *(const short4v*)(vr0 + 16);  v10.h[1] = *(const short4v*)(vr0 + 24);
        v11.h[0] = *(const short4v*)(vr1 + 16);  v11.h[1] = *(const short4v*)(vr1 + 24);
        acc0 = __builtin_amdgcn_mfma_f32_32x32x16_bf16(v00.v, bf0.v, acc0, 0, 0, 0);
        acc1 = __builtin_amdgcn_mfma_f32_32x32x16_bf16(v01.v, bf0.v, acc1, 0, 0, 0);
        acc0 = __builtin_amdgcn_mfma_f32_32x32x16_bf16(v10.v, bf1.v, acc0, 0, 0, 0);
        acc1 = __builtin_amdgcn_mfma_f32_32x32x16_bf16(v11.v, bf1.v, acc1, 0, 0, 0);
    }
    float* rd = &red[w][l][0];
    rd[0] = m; rd[1] = lsum;
    #pragma unroll
    for (int r = 0; r < 16; ++r) rd[2 + r]  = acc0[r];
    #pragma unroll
    for (int r = 0; r < 4; ++r)  rd[18 + r] = acc1[r];
    __syncthreads();
    {
        const int l2 = t & 63, g = t >> 6;
        const int li2 = l2 & 31, hf2 = l2 >> 5;
        float ms = -1e30f;
        #pragma unroll
        for (int ww = 0; ww < 8; ++ww) ms = fmaxf(ms, red[ww][l2][0]);
        float wt[8]; float lf = 0.f;
        #pragma unroll
        for (int ww = 0; ww < 8; ++ww) {
            wt[ww] = __expf(red[ww][l2][0] - ms);
            lf += wt[ww] * red[ww][l2][1];
        }
        float inv = 1.f / lf;
        const int n = i0 + li2;
        #pragma unroll
        for (int rr = 0; rr < 3; ++rr) {
            int r = g + rr * 8;
            if (r < 20) {
                float v = 0.f;
                #pragma unroll
                for (int ww = 0; ww < 8; ++ww) v += wt[ww] * red[ww][l2][2 + r];
                v *= inv;
                int d = (r < 16) ? ((r & 3) + 8 * (r >> 2) + 4 * hf2)
                                 : (32 + (r - 16) + 4 * hf2);
                unsigned short ov = f2b(v);
                if (d < 16) Og [((long)(b * N_ + n)) * 192 + hh * 16 + d] = ov;
                else        OPg[((long)(b * N_ + n)) * 288 + hh * 24 + (d - 16)] = ov;
            }
        }
    }
}

// ============================================================
// cat build: inverse rotation + norms -> CATT[48][72][32][8] (chunk-interleaved)
// ============================================================
__global__ __launch_bounds__(128) void cat_kernel(
    const unsigned short* __restrict__ Og, const unsigned short* __restrict__ OPg,
    const float* __restrict__ rot, const float* __restrict__ trans,
    unsigned short* __restrict__ catgT)
{
    __shared__ float cat[576];
    __shared__ float rt[12];
    const int bn = blockIdx.x;
    const int t  = threadIdx.x;
    if (t < 9) rt[t]     = rot[bn * 9 + t];
    if (t < 3) rt[9 + t] = trans[bn * 3 + t];
    for (int d = t; d < 192; d += 128) cat[d] = b2f(Og[(long)bn * 192 + d]);
    __syncthreads();
    if (t < 96) {
        float g0 = b2f(OPg[(long)bn * 288 + t * 3 + 0]) - rt[9];
        float g1 = b2f(OPg[(long)bn * 288 + t * 3 + 1]) - rt[10];
        float g2 = b2f(OPg[(long)bn * 288 + t * 3 + 2]) - rt[11];
        float l0 = rt[0]*g0 + rt[3]*g1 + rt[6]*g2;
        float l1 = rt[1]*g0 + rt[4]*g1 + rt[7]*g2;
        float l2 = rt[2]*g0 + rt[5]*g1 + rt[8]*g2;
        cat[192 + t] = l0;
        cat[288 + t] = l1;
        cat[384 + t] = l2;
        cat[480 + t] = sqrtf(l0*l0 + l1*l1 + l2*l2 + EPS_);
    }
    __syncthreads();
    const long sbase = ((long)(bn >> 5)) * 72 * 256 + (bn & 31) * 8;
    for (int d = t; d < 576; d += 128)
        catgT[sbase + (long)(d >> 3) * 256 + (d & 7)] = f2b(cat[d]);
}

// ============================================================
// output GEMM (MFMA, interleaved operands): out = cat @ w_out^T + b_out
// ============================================================
__global__ __launch_bounds__(64) void out_mfma(
    const unsigned short* __restrict__ catgT,  // [48][72][32][8]
    const unsigned short* __restrict__ WOBT,   // [12][72][32][8]
    const float* __restrict__ b_out,
    float* __restrict__ out)
{
    const int tile = blockIdx.x;          // 48 * 12
    const int tn = tile % 12, tm = tile / 12;
    const int r0 = tm * 32, c0 = tn * 32;
    const int l  = threadIdx.x;
    const int li = l & 31, hf = l >> 5;

    const unsigned short* ab = catgT + (long)tm * 72 * 256;
    const unsigned short* wb = WOBT  + (long)tn * 72 * 256;

    f32x16 acc = {};
    for (int k = 0; k < 576; k += 32) {
        const int c = (k >> 3) + hf;
        short8 a0 = *(const short8*)(ab + (c * 32 + li) * 8);
        short8 a1 = *(const short8*)(ab + ((c + 2) * 32 + li) * 8);
        short8 b0 = *(const short8*)(wb + (c * 32 + li) * 8);
        short8 b1 = *(const short8*)(wb + ((c + 2) * 32 + li) * 8);
        acc = __builtin_amdgcn_mfma_f32_32x32x16_bf16(a0, b0, acc, 0, 0, 0);
        acc = __builtin_amdgcn_mfma_f32_32x32x16_bf16(a1, b1, acc, 0, 0, 0);
    }
    float bias = b_out[c0 + li];
    #pragma unroll
    for (int r = 0; r < 16; ++r) {
        int row = r0 + (r & 3) + 8 * (r >> 2) + 4 * hf;
        out[(long)row * 384 + c0 + li] = acc[r] + bias;
    }
}

// ============================================================
extern "C" void kernel_launch(void* const* d_in, const int* in_sizes, int n_in,
                              void* d_out, int out_size, void* d_ws, size_t ws_size,
                              hipStream_t stream) {
    const float* s            = (const float*)d_in[0];
    const float* rot          = (const float*)d_in[1];
    const float* trans        = (const float*)d_in[2];
    const float* pair_mask    = (const float*)d_in[3];
    const float* w_q          = (const float*)d_in[4];
    const float* b_q          = (const float*)d_in[5];
    const float* w_kv         = (const float*)d_in[6];
    const float* b_kv         = (const float*)d_in[7];
    const float* w_qp         = (const float*)d_in[8];
    const float* b_qp         = (const float*)d_in[9];
    const float* w_kvp        = (const float*)d_in[10];
    const float* b_kvp        = (const float*)d_in[11];
    const float* head_weights = (const float*)d_in[12];
    const float* w_out        = (const float*)d_in[13];
    const float* b_out        = (const float*)d_in[14];
    float* out = (float*)d_out;
    float* ws  = (float*)d_ws;

    float*          PROJP = ws + OFF_PROJP;
    unsigned short* Og   = (unsigned short*)(ws + OFF_O);
    unsigned short* OPg  = (unsigned short*)(ws + OFF_OP);
    unsigned short* CATT = (unsigned short*)(ws + OFF_CAT);
    unsigned short* Qf   = (unsigned short*)(ws + OFF_QF);
    unsigned short* Kf   = (unsigned short*)(ws + OFF_KF);
    unsigned short* Vt   = (unsigned short*)(ws + OFF_VT);
    unsigned short* SB   = (unsigned short*)(ws + OFF_SB);
    unsigned short* WB   = (unsigned short*)(ws + OFF_WB);
    unsigned short* WOBT = (unsigned short*)(ws + OFF_WOB);
    unsigned short* MBp  = (unsigned short*)(ws + OFF_MB);

    prep_kernel<<<1224, 256, 0, stream>>>(s, w_q, w_kv, w_qp, w_kvp, w_out,
                                          SB, WB, WOBT);
    proj_mb_kernel<<<48 * 36 + B_ * 24 * 24, 64, 0, stream>>>(
        SB, WB, b_q, b_kv, b_qp, b_kvp, pair_mask, PROJP, Qf, Kf, Vt, MBp);
    pack3_kernel<<<B_ * N_, 128, 0, stream>>>(PROJP, rot, trans, head_weights,
                                              Qf, Kf, Vt);
    attn2_kernel<<<B_ * H_ * 24, 512, 0, stream>>>(Qf, Kf, Vt, MBp, Og, OPg);
    cat_kernel<<<B_ * N_, 128, 0, stream>>>(Og, OPg, rot, trans, CATT);
    out_mfma<<<48 * 12, 64, 0, stream>>>(CATT, WOBT, b_out, out);
}

// Round 12
// 56.234 us; speedup vs baseline: 1.8124x; 1.0259x over previous
//
#include <hip/hip_runtime.h>
#include <hip/hip_bf16.h>
#include <math.h>

typedef __attribute__((ext_vector_type(4)))  short short4v;
typedef __attribute__((ext_vector_type(8)))  short short8;
typedef __attribute__((ext_vector_type(16))) float f32x16;

#define B_   2
#define N_   768
#define CN_  384
#define H_   12
#define INF_ 100000.0f
#define EPS_ 1e-7f

// ---------------- workspace layout (f32-slot offsets) ----------------
// PROJP f32 [1536][576]       at 0        (point-proj columns + bias; dead after pack3)
// OPg bf16 [1536][288]        at 1032192
// CATT bf16 [48][72][32][8]   at 1253376  (chunk-interleaved; chunks 0..23 = o-part,
//     written directly by attn2's merge; chunks 24..71 never touched in global)
// Qf  bf16 [24][768][32]      at 1769472
// Kf  bf16 [24][768][32]      at 2064384
// VtT bf16 [24][24][64][32]   at 2359296  (tile-interleaved; d rows 40..63
//     never written: garbage confined to discarded acc1 regs 4..15)
// SB  bf16 [1536][384]        at 2949120
// WB  bf16 [1152][384]        at 3244032
// WOBT bf16 [12][72][32][8]   at 3465216  (chunk-interleaved w_out)
// MB  bf16 [2][24][24][64][16] at 3575808
#define OFF_PROJP 0
#define OFF_OP    1032192
#define OFF_CAT   1253376
#define OFF_QF    1769472
#define OFF_KF    2064384
#define OFF_VT    2359296
#define OFF_SB    2949120
#define OFF_WB    3244032
#define OFF_WOB   3465216
#define OFF_MB    3575808

__device__ inline float b2f(unsigned short u) {
    union { unsigned int i; float f; } x; x.i = ((unsigned int)u) << 16; return x.f;
}
__device__ inline unsigned short f2b(float f) {
    __hip_bfloat16 h = __float2bfloat16(f);
    return *reinterpret_cast<unsigned short*>(&h);
}

// ============================================================
// prep: fp32 -> bf16 operand conversion (s, Wcat rows, w_out->WOBT interleaved)
// ============================================================
__global__ __launch_bounds__(256) void prep_kernel(
    const float* __restrict__ s,
    const float* __restrict__ w_q,  const float* __restrict__ w_kv,
    const float* __restrict__ w_qp, const float* __restrict__ w_kvp,
    const float* __restrict__ w_out,
    unsigned short* __restrict__ SB, unsigned short* __restrict__ WB,
    unsigned short* __restrict__ WOBT)
{
    const long i4 = ((long)blockIdx.x * 256 + threadIdx.x) * 4;
    const float* src; unsigned short* dst; long off;
    if (i4 < 589824) {
        src = s + i4; dst = SB; off = i4;
    } else if (i4 < 1032192) {
        long e = i4 - 589824;
        int row = (int)(e / 384), c = (int)(e - (long)row * 384);
        const float* wsrc;
        if (row < 192)      wsrc = w_q   + (long)row * 384;
        else if (row < 576) wsrc = w_kv  + (long)(row - 192) * 384;
        else if (row < 720) wsrc = w_qp  + (long)(row - 576) * 384;
        else                wsrc = w_kvp + (long)(row - 720) * 384;
        src = wsrc + c; dst = WB; off = e;
    } else {
        long e = i4 - 1032192;           // element in w_out [384][576]
        int row = (int)(e / 576), c = (int)(e - (long)row * 576);
        src = w_out + e; dst = WOBT;
        off = (((long)(row >> 5) * 72 + (c >> 3)) * 32 + (row & 31)) * 8 + (c & 7);
    }
    float4 v = *(const float4*)src;
    short4v o;
    o[0] = (short)f2b(v.x); o[1] = (short)f2b(v.y);
    o[2] = (short)f2b(v.z); o[3] = (short)f2b(v.w);
    *(short4v*)(dst + off) = o;
}

// ============================================================
// fused: projection GEMM (MFMA, blocks 0..1727) + mask-bias pack (1728..2879)
// ============================================================
__global__ __launch_bounds__(64) void proj_mb_kernel(
    const unsigned short* __restrict__ SB, const unsigned short* __restrict__ WB,
    const float* __restrict__ b_q,  const float* __restrict__ b_kv,
    const float* __restrict__ b_qp, const float* __restrict__ b_kvp,
    const float* __restrict__ mask,
    float* __restrict__ PROJP, unsigned short* __restrict__ Qf,
    unsigned short* __restrict__ Kf, unsigned short* __restrict__ Vt,
    unsigned short* __restrict__ MB)
{
    if (blockIdx.x >= 1728) {
        // ---- mask-bias pack ----
        const int tile = blockIdx.x - 1728;   // b*576 + it*24 + jt
        const int jt = tile % 24;
        const int it = (tile / 24) % 24;
        const int b  = tile / 576;
        const int tt = threadIdx.x;           // == l
        const int i0 = it * 32, j0 = jt * 32;
        const float* mrow = mask + ((long)b * N_ + i0 + (tt & 31)) * N_
                          + j0 + (tt >> 5) * 4;
        union { unsigned short u[16]; short8 v[2]; } o;
        #pragma unroll
        for (int g = 0; g < 4; ++g) {         // j-groups 0,8,16,24
            float4 mv = *(const float4*)(mrow + 8 * g);
            o.u[g*4+0] = f2b(INF_ * (mv.x - 1.f));
            o.u[g*4+1] = f2b(INF_ * (mv.y - 1.f));
            o.u[g*4+2] = f2b(INF_ * (mv.z - 1.f));
            o.u[g*4+3] = f2b(INF_ * (mv.w - 1.f));
        }
        unsigned short* outp = MB + (long)tile * 1024 + tt * 16;
        *(short8*)(outp)     = o.v[0];
        *(short8*)(outp + 8) = o.v[1];
        return;
    }
    // ---- projection GEMM ----
    const int tile = blockIdx.x;          // 48 * 36
    const int tn = tile % 36, tm = tile / 36;
    const int r0 = tm * 32, c0 = tn * 32;
    const int l  = threadIdx.x;
    const int li = l & 31, hf = l >> 5;

    const unsigned short* ap = SB + (long)(r0 + li) * CN_ + hf * 8;
    const int col = c0 + li;
    const unsigned short* wb = WB + (long)col * CN_ + hf * 8;
    const float bias = (col < 192) ? b_q[col] : (col < 576) ? b_kv[col - 192]
                     : (col < 720) ? b_qp[col - 576] : b_kvp[col - 720];

    f32x16 acc = {};
    for (int k = 0; k < CN_; k += 32) {
        short8 a0 = *(const short8*)(ap + k);
        short8 a1 = *(const short8*)(ap + k + 16);
        short8 b0 = *(const short8*)(wb + k);
        short8 b1 = *(const short8*)(wb + k + 16);
        acc = __builtin_amdgcn_mfma_f32_32x32x16_bf16(a0, b0, acc, 0, 0, 0);
        acc = __builtin_amdgcn_mfma_f32_32x32x16_bf16(a1, b1, acc, 0, 0, 0);
    }
    const int row_b = r0 / N_;            // uniform: 768 % 32 == 0
    if (tn < 6) {                         // q tile
        const int hq = col >> 4, c = col & 15;
        const long qb = (long)(row_b * H_ + hq) * N_;
        #pragma unroll
        for (int r = 0; r < 16; ++r) {
            int row = r0 + (r & 3) + 8 * (r >> 2) + 4 * hf;
            int n = row - row_b * N_;
            Qf[(qb + n) * 32 + c] = f2b((acc[r] + bias) * 0.144337567297406f);
        }
    } else if (tn < 18) {                 // kv tile, h = tn-6 uniform
        const int hkv = tn - 6;
        const long kb = (long)(row_b * H_ + hkv) * N_;
        const long vb = (long)(row_b * H_ + hkv) * 24;
        #pragma unroll
        for (int r = 0; r < 16; ++r) {
            int row = r0 + (r & 3) + 8 * (r >> 2) + 4 * hf;
            int n = row - row_b * N_;
            unsigned short v = f2b(acc[r] + bias);
            if (li < 16) Kf[(kb + n) * 32 + li] = v;
            else Vt[((vb + (n >> 5)) * 64 + (li - 16)) * 32 + (n & 31)] = v;
        }
    } else {                              // point tile -> PROJP fp32
        const int pc = col - 576;
        #pragma unroll
        for (int r = 0; r < 16; ++r) {
            int row = r0 + (r & 3) + 8 * (r >> 2) + 4 * hf;
            PROJP[(long)row * 576 + pc] = acc[r] + bias;
        }
    }
}

// ============================================================
// pack3: rotations only. One block (128 thr) per (b,n).
// ============================================================
__global__ __launch_bounds__(128) void pack3_kernel(
    const float* __restrict__ PROJP,
    const float* __restrict__ rot, const float* __restrict__ trans,
    const float* __restrict__ head_weights,
    unsigned short* __restrict__ Qf, unsigned short* __restrict__ Kf,
    unsigned short* __restrict__ Vt)
{
    __shared__ float pp[576];
    __shared__ float rt[12];
    __shared__ float hws[12];
    __shared__ float kp2[48];
    const int bn = blockIdx.x;
    const int t  = threadIdx.x;
    const float4* src = (const float4*)(PROJP + (long)bn * 576);
    for (int d = t; d < 144; d += 128) ((float4*)pp)[d] = src[d];
    if (t < 9) rt[t]     = rot[bn * 9 + t];
    if (t < 3) rt[9 + t] = trans[bn * 3 + t];
    if (t < 12) {
        float v  = head_weights[t];
        float sp = (v > 20.f) ? v : log1pf(expf(v));
        hws[t] = sp * 0.13608276348795434f;  // softplus * sqrt(1/54)
    }
    __syncthreads();
    const int b = bn / N_, n = bn % N_;
    for (int e = t; e < 192; e += 128) {
        if (e < 48) {                     // qp point (h, p)
            int h = e >> 2, p = e & 3;
            float r0 = pp[     h * 4 + p];
            float r1 = pp[48 + h * 4 + p];
            float r2 = pp[96 + h * 4 + p];
            long base = ((long)(b * H_ + h) * N_ + n) * 32;
            #pragma unroll
            for (int x = 0; x < 3; ++x) {
                float o = rt[x*3]*r0 + rt[x*3+1]*r1 + rt[x*3+2]*r2 + rt[9+x];
                Qf[base + 16 + p * 3 + x] = f2b(o * hws[h]);
            }
        } else {                          // kvp point (h, pi)
            int idx = e - 48;
            int h = idx / 12, pi = idx - h * 12;
            float r0 = pp[144 +       h * 12 + pi];
            float r1 = pp[144 + 144 + h * 12 + pi];
            float r2 = pp[144 + 288 + h * 12 + pi];
            float o0 = rt[0]*r0 + rt[1]*r1 + rt[2]*r2 + rt[9];
            float o1 = rt[3]*r0 + rt[4]*r1 + rt[5]*r2 + rt[10];
            float o2 = rt[6]*r0 + rt[7]*r1 + rt[8]*r2 + rt[11];
            if (pi < 4) {
                long base = ((long)(b * H_ + h) * N_ + n) * 32;
                Kf[base + 16 + pi * 3 + 0] = f2b(o0);
                Kf[base + 16 + pi * 3 + 1] = f2b(o1);
                Kf[base + 16 + pi * 3 + 2] = f2b(o2);
                kp2[h * 4 + pi] = o0*o0 + o1*o1 + o2*o2;
            } else {
                int dd = 16 + (pi - 4) * 3;
                long vb = ((long)(b * H_ + h) * 24 + (n >> 5)) * 64;
                Vt[(vb + dd + 0) * 32 + (n & 31)] = f2b(o0);
                Vt[(vb + dd + 1) * 32 + (n & 31)] = f2b(o1);
                Vt[(vb + dd + 2) * 32 + (n & 31)] = f2b(o2);
            }
        }
    }
    __syncthreads();
    if (t < 12) {
        float s2 = kp2[t*4] + kp2[t*4+1] + kp2[t*4+2] + kp2[t*4+3];
        float kc = -0.5f * hws[t] * s2;
        long base = ((long)(b * H_ + t) * N_ + n) * 32;
        unsigned short hi = f2b(kc);
        Kf[base + 28] = hi;
        Kf[base + 29] = f2b(kc - b2f(hi));
        Kf[base + 30] = 0; Kf[base + 31] = 0;
        unsigned short one = f2b(1.f);
        Qf[base + 28] = one; Qf[base + 29] = one;
        Qf[base + 30] = 0;   Qf[base + 31] = 0;
    }
}

// ============================================================
// MFMA flash attention. Grid (b*12+h)*24+it, 512 threads = 8 waves.
// Merge writes o-part DIRECTLY into CATT chunk-interleaved (chunks 0..23);
// point-part still goes to OPg. (b*N_+i0)>>5 == b*24+it.
// ============================================================
__global__ __launch_bounds__(512) void attn2_kernel(
    const unsigned short* __restrict__ Qf, const unsigned short* __restrict__ Kf,
    const unsigned short* __restrict__ Vt, const unsigned short* __restrict__ MB,
    unsigned short* __restrict__ CATT, unsigned short* __restrict__ OPg)
{
    __shared__ float red[8][64][23];   // 23: odd stride -> conflict-free merge
    const int blk = blockIdx.x;
    const int it = blk % 24;
    const int bh = blk / 24;
    const int hh = bh % 12;
    const int b  = bh / 12;
    const int t  = threadIdx.x;
    const int w  = t >> 6;
    const int l  = t & 63;
    const int li = l & 31;
    const int hf = l >> 5;
    const int i0 = it * 32;

    const unsigned short* qbase = Qf + ((long)bh * N_ + i0 + li) * 32 + hf * 8;
    short8 q0 = *(const short8*)(qbase);
    short8 q1 = *(const short8*)(qbase + 16);

    f32x16 acc0 = {};
    f32x16 acc1 = {};
    float m = -1e30f, lsum = 0.f;
    const unsigned short* vtb = Vt + (long)bh * 24 * 2048;
    const unsigned short* mbb = MB + ((long)(b * 24 + it)) * 24 * 1024;

    for (int jt = w * 3; jt < w * 3 + 3; ++jt) {
        const int j0 = jt * 32;
        const unsigned short* mbp = mbb + (long)jt * 1024 + l * 16;
        short8 mb0 = *(const short8*)(mbp);
        short8 mb1 = *(const short8*)(mbp + 8);
        f32x16 S;
        #pragma unroll
        for (int r = 0; r < 8; ++r) S[r]     = b2f((unsigned short)mb0[r]);
        #pragma unroll
        for (int r = 0; r < 8; ++r) S[8 + r] = b2f((unsigned short)mb1[r]);
        const unsigned short* kp = Kf + ((long)bh * N_ + j0 + li) * 32 + hf * 8;
        short8 k0 = *(const short8*)(kp);
        short8 k1 = *(const short8*)(kp + 16);
        S = __builtin_amdgcn_mfma_f32_32x32x16_bf16(k0, q0, S, 0, 0, 0);
        S = __builtin_amdgcn_mfma_f32_32x32x16_bf16(k1, q1, S, 0, 0, 0);
        float mloc = S[0];
        #pragma unroll
        for (int r = 1; r < 16; ++r) mloc = fmaxf(mloc, S[r]);
        {
            auto mm = __builtin_amdgcn_permlane32_swap(
                __float_as_int(mloc), __float_as_int(mloc), false, false);
            mloc = fmaxf(__int_as_float(mm[0]), __int_as_float(mm[1]));
        }
        float newm = fmaxf(m, mloc);
        float scale = __expf(m - newm);
        float ps = 0.f;
        f32x16 p;
        #pragma unroll
        for (int r = 0; r < 16; ++r) { p[r] = __expf(S[r] - newm); ps += p[r]; }
        {
            auto ss = __builtin_amdgcn_permlane32_swap(
                __float_as_int(ps), __float_as_int(ps), false, false);
            ps = __int_as_float(ss[0]) + __int_as_float(ss[1]);
        }
        lsum = lsum * scale + ps;
        m = newm;
        #pragma unroll
        for (int r = 0; r < 16; ++r) acc0[r] *= scale;
        #pragma unroll
        for (int r = 0; r < 4; ++r)  acc1[r] *= scale;
        int c[8];
        #pragma unroll
        for (int r = 0; r < 8; ++r) {
            asm("v_cvt_pk_bf16_f32 %0, %1, %2" : "=v"(c[r]) : "v"(p[2*r]), "v"(p[2*r+1]));
        }
        union { int w4[4]; short8 v; } bf0, bf1;
        bf0.w4[0] = c[0]; bf0.w4[1] = c[1]; bf0.w4[2] = c[2]; bf0.w4[3] = c[3];
        bf1.w4[0] = c[4]; bf1.w4[1] = c[5]; bf1.w4[2] = c[6]; bf1.w4[3] = c[7];
        const unsigned short* tb  = vtb + jt * 2048;
        const unsigned short* vr0 = tb + li * 32 + hf * 4;
        const unsigned short* vr1 = tb + (32 + li) * 32 + hf * 4;
        union { short4v h[2]; short8 v; } v00, v01, v10, v11;
        v00.h[0] = *(const short4v*)(vr0);       v00.h[1] = *(const short4v*)(vr0 + 8);
        v01.h[0] = *(const short4v*)(vr1);       v01.h[1] = *(const short4v*)(vr1 + 8);
        v10.h[0] = *(const short4v*)(vr0 + 16);  v10.h[1] = *(const short4v*)(vr0 + 24);
        v11.h[0] = *(const short4v*)(vr1 + 16);  v11.h[1] = *(const short4v*)(vr1 + 24);
        acc0 = __builtin_amdgcn_mfma_f32_32x32x16_bf16(v00.v, bf0.v, acc0, 0, 0, 0);
        acc1 = __builtin_amdgcn_mfma_f32_32x32x16_bf16(v01.v, bf0.v, acc1, 0, 0, 0);
        acc0 = __builtin_amdgcn_mfma_f32_32x32x16_bf16(v10.v, bf1.v, acc0, 0, 0, 0);
        acc1 = __builtin_amdgcn_mfma_f32_32x32x16_bf16(v11.v, bf1.v, acc1, 0, 0, 0);
    }
    float* rd = &red[w][l][0];
    rd[0] = m; rd[1] = lsum;
    #pragma unroll
    for (int r = 0; r < 16; ++r) rd[2 + r]  = acc0[r];
    #pragma unroll
    for (int r = 0; r < 4; ++r)  rd[18 + r] = acc1[r];
    __syncthreads();
    {
        const int l2 = t & 63, g = t >> 6;
        const int li2 = l2 & 31, hf2 = l2 >> 5;
        float ms = -1e30f;
        #pragma unroll
        for (int ww = 0; ww < 8; ++ww) ms = fmaxf(ms, red[ww][l2][0]);
        float wt[8]; float lf = 0.f;
        #pragma unroll
        for (int ww = 0; ww < 8; ++ww) {
            wt[ww] = __expf(red[ww][l2][0] - ms);
            lf += wt[ww] * red[ww][l2][1];
        }
        float inv = 1.f / lf;
        const int n = i0 + li2;
        const long ctile = ((long)(b * 24 + it)) * 72 * 256 + li2 * 8;
        #pragma unroll
        for (int rr = 0; rr < 3; ++rr) {
            int r = g + rr * 8;
            if (r < 20) {
                float v = 0.f;
                #pragma unroll
                for (int ww = 0; ww < 8; ++ww) v += wt[ww] * red[ww][l2][2 + r];
                v *= inv;
                int d = (r < 16) ? ((r & 3) + 8 * (r >> 2) + 4 * hf2)
                                 : (32 + (r - 16) + 4 * hf2);
                unsigned short ov = f2b(v);
                if (d < 16) {
                    int c = hh * 16 + d;
                    CATT[ctile + (long)(c >> 3) * 256 + (c & 7)] = ov;
                } else {
                    OPg[((long)(b * N_ + n)) * 288 + hh * 24 + (d - 16)] = ov;
                }
            }
        }
    }
}

// ============================================================
// fused point-cat build + output GEMM. 144 blocks x 256 thr (4 waves).
// Block (tm, tng): rows r0=tm*32, waves handle tn = tng*4 + wv.
// Phase A: stage OPg tile + rot/trans.  Phase B: 3072 rotations flat.
// Phase C: k<192 A-chunks from CATT global (o-part, written by attn2);
//          k>=192 A-chunks from LDS catp. All reads lane-contiguous.
// ============================================================
__global__ __launch_bounds__(256) void out_fused2(
    const unsigned short* __restrict__ CATT, const unsigned short* __restrict__ OPg,
    const float* __restrict__ rot, const float* __restrict__ trans,
    const unsigned short* __restrict__ WOBT, const float* __restrict__ b_out,
    float* __restrict__ out)
{
    __shared__ unsigned short op_s[32][288];
    __shared__ unsigned short catp[48][32][8];
    __shared__ float rt_s[32][12];
    const int blk = blockIdx.x;           // 48 * 3
    const int tm = blk / 3, tng = blk % 3;
    const int r0 = tm * 32;
    const int t  = threadIdx.x;

    for (int e = t; e < 32 * 36; e += 256) {
        int rr = e / 36, c8 = e - rr * 36;
        *(short8*)&op_s[rr][c8 * 8] = *(const short8*)(OPg + (long)(r0 + rr) * 288 + c8 * 8);
    }
    for (int e = t; e < 32 * 12; e += 256) {
        int rr = e / 12, c = e - rr * 12;
        rt_s[rr][c] = (c < 9) ? rot[(long)(r0 + rr) * 9 + c]
                              : trans[(long)(r0 + rr) * 3 + (c - 9)];
    }
    __syncthreads();
    for (int e = t; e < 3072; e += 256) {
        int rr = e / 96, pt = e - (e / 96) * 96;
        const float* rp = rt_s[rr];
        float g0 = b2f(op_s[rr][pt * 3 + 0]) - rp[9];
        float g1 = b2f(op_s[rr][pt * 3 + 1]) - rp[10];
        float g2 = b2f(op_s[rr][pt * 3 + 2]) - rp[11];
        float l0 = rp[0]*g0 + rp[3]*g1 + rp[6]*g2;
        float l1 = rp[1]*g0 + rp[4]*g1 + rp[7]*g2;
        float l2 = rp[2]*g0 + rp[5]*g1 + rp[8]*g2;
        int c;
        c = 192 + pt; catp[(c >> 3) - 24][rr][c & 7] = f2b(l0);
        c = 288 + pt; catp[(c >> 3) - 24][rr][c & 7] = f2b(l1);
        c = 384 + pt; catp[(c >> 3) - 24][rr][c & 7] = f2b(l2);
        c = 480 + pt; catp[(c >> 3) - 24][rr][c & 7] = f2b(sqrtf(l0*l0 + l1*l1 + l2*l2 + EPS_));
    }
    __syncthreads();
    const int wv = t >> 6, l = t & 63;
    const int li = l & 31, hf = l >> 5;
    const int tn = tng * 4 + wv;
    const unsigned short* ab = CATT + (long)tm * 72 * 256;
    const unsigned short* wb = WOBT + (long)tn * 72 * 256;
    f32x16 acc = {};
    for (int k = 0; k < 192; k += 32) {       // o-part: A from global CATT
        const int c = (k >> 3) + hf;
        short8 a0 = *(const short8*)(ab + (c * 32 + li) * 8);
        short8 a1 = *(const short8*)(ab + ((c + 2) * 32 + li) * 8);
        short8 b0 = *(const short8*)(wb + (c * 32 + li) * 8);
        short8 b1 = *(const short8*)(wb + ((c + 2) * 32 + li) * 8);
        acc = __builtin_amdgcn_mfma_f32_32x32x16_bf16(a0, b0, acc, 0, 0, 0);
        acc = __builtin_amdgcn_mfma_f32_32x32x16_bf16(a1, b1, acc, 0, 0, 0);
    }
    for (int k = 192; k < 576; k += 32) {     // point-part: A from LDS
        const int cg = (k >> 3) + hf;
        const int cl = cg - 24;
        short8 a0 = *(const short8*)&catp[cl][li][0];
        short8 a1 = *(const short8*)&catp[cl + 2][li][0];
        short8 b0 = *(const short8*)(wb + (cg * 32 + li) * 8);
        short8 b1 = *(const short8*)(wb + ((cg + 2) * 32 + li) * 8);
        acc = __builtin_amdgcn_mfma_f32_32x32x16_bf16(a0, b0, acc, 0, 0, 0);
        acc = __builtin_amdgcn_mfma_f32_32x32x16_bf16(a1, b1, acc, 0, 0, 0);
    }
    float bias = b_out[tn * 32 + li];
    #pragma unroll
    for (int r = 0; r < 16; ++r) {
        int row = r0 + (r & 3) + 8 * (r >> 2) + 4 * hf;
        out[(long)row * 384 + tn * 32 + li] = acc[r] + bias;
    }
}

// ============================================================
extern "C" void kernel_launch(void* const* d_in, const int* in_sizes, int n_in,
                              void* d_out, int out_size, void* d_ws, size_t ws_size,
                              hipStream_t stream) {
    const float* s            = (const float*)d_in[0];
    const float* rot          = (const float*)d_in[1];
    const float* trans        = (const float*)d_in[2];
    const float* pair_mask    = (const float*)d_in[3];
    const float* w_q          = (const float*)d_in[4];
    const float* b_q          = (const float*)d_in[5];
    const float* w_kv         = (const float*)d_in[6];
    const float* b_kv         = (const float*)d_in[7];
    const float* w_qp         = (const float*)d_in[8];
    const float* b_qp         = (const float*)d_in[9];
    const float* w_kvp        = (const float*)d_in[10];
    const float* b_kvp        = (const float*)d_in[11];
    const float* head_weights = (const float*)d_in[12];
    const float* w_out        = (const float*)d_in[13];
    const float* b_out        = (const float*)d_in[14];
    float* out = (float*)d_out;
    float* ws  = (float*)d_ws;

    float*          PROJP = ws + OFF_PROJP;
    unsigned short* OPg  = (unsigned short*)(ws + OFF_OP);
    unsigned short* CATT = (unsigned short*)(ws + OFF_CAT);
    unsigned short* Qf   = (unsigned short*)(ws + OFF_QF);
    unsigned short* Kf   = (unsigned short*)(ws + OFF_KF);
    unsigned short* Vt   = (unsigned short*)(ws + OFF_VT);
    unsigned short* SB   = (unsigned short*)(ws + OFF_SB);
    unsigned short* WB   = (unsigned short*)(ws + OFF_WB);
    unsigned short* WOBT = (unsigned short*)(ws + OFF_WOB);
    unsigned short* MBp  = (unsigned short*)(ws + OFF_MB);

    prep_kernel<<<1224, 256, 0, stream>>>(s, w_q, w_kv, w_qp, w_kvp, w_out,
                                          SB, WB, WOBT);
    proj_mb_kernel<<<48 * 36 + B_ * 24 * 24, 64, 0, stream>>>(
        SB, WB, b_q, b_kv, b_qp, b_kvp, pair_mask, PROJP, Qf, Kf, Vt, MBp);
    pack3_kernel<<<B_ * N_, 128, 0, stream>>>(PROJP, rot, trans, head_weights,
                                              Qf, Kf, Vt);
    attn2_kernel<<<B_ * H_ * 24, 512, 0, stream>>>(Qf, Kf, Vt, MBp, CATT, OPg);
    out_fused2<<<48 * 3, 256, 0, stream>>>(CATT, OPg, rot, trans, WOBT, b_out, out);
}